// Round 2
// baseline (743.349 us; speedup 1.0000x reference)
//
#include <hip/hip_runtime.h>
#include <math.h>

// GlobalAdaptiveDecoder: B=32 S=64 D=512 H=8 DK=DV=64 NR=196 L=6 VOCAB=10000
// Round 5 (resubmit): prep rewritten — vectorized transposes (float4 loads,
// short8 stores, LDS 64x65 tile with 2-way-free banks both phases) and fp32
// positional encoding (was per-element fp64 exp/log/sin/cos). 17 launches.

#define S2 (512*512)
typedef unsigned short ushort_t;
typedef unsigned int u32;
typedef __attribute__((ext_vector_type(8))) short short8;
typedef __attribute__((ext_vector_type(4))) float f32x4;

__device__ __forceinline__ ushort_t f2b(float f) {
    union { float f; u32 u; } v; v.f = f;
    u32 r = (v.u + 0x7fffu + ((v.u >> 16) & 1u)) >> 16;
    return (ushort_t)r;
}
__device__ __forceinline__ float b2f(ushort_t u) {
    union { u32 u; float f; } v; v.u = ((u32)u) << 16; return v.f;
}
__device__ __forceinline__ void glds16(const void* g, void* l) {
    __builtin_amdgcn_global_load_lds((const __attribute__((address_space(1))) u32*)g,
                                     (__attribute__((address_space(3))) u32*)l,
                                     16, 0, 0);
}
__device__ __forceinline__ f32x4 mfma16(short8 a, short8 b, f32x4 c) {
    return __builtin_amdgcn_mfma_f32_16x16x32_bf16(a, b, c, 0, 0, 0);
}

// ---------------------------------------------------------------------------
// 128x128 MFMA tile body (shared by gemm_bt / fusew). C = A @ B^T (+bias),
// bf16 out via LDS-coalesced epilogue. Rows covered by grid; N mult of 8.
// ---------------------------------------------------------------------------
__device__ __forceinline__ void tile128(
    const ushort_t* __restrict__ A, const ushort_t* __restrict__ B,
    ushort_t* __restrict__ Cp, int N, int K, const float* __restrict__ biasc,
    int m0, int n0, ushort_t* As, ushort_t* Bs, ushort_t* Cs)
{
    int t = threadIdx.x;
    int sr = t >> 2, sk = (t & 3) * 8;
    int wv = t >> 6, lane = t & 63;
    int wr = (wv >> 1) * 64, wc = (wv & 1) * 64;
    int lr = lane & 15, lq = lane >> 4;

    f32x4 acc[4][4];
#pragma unroll
    for (int i = 0; i < 4; ++i)
#pragma unroll
        for (int j = 0; j < 4; ++j) acc[i][j] = (f32x4){0.f, 0.f, 0.f, 0.f};

    for (int k0 = 0; k0 < K; k0 += 32) {
        glds16(A + (long)(m0 + sr) * K + k0 + sk,      (void*)(As + t * 8));
        glds16(A + (long)(m0 + sr + 64) * K + k0 + sk, (void*)(As + (t + 256) * 8));
        glds16(B + (long)(n0 + sr) * K + k0 + sk,      (void*)(Bs + t * 8));
        glds16(B + (long)(n0 + sr + 64) * K + k0 + sk, (void*)(Bs + (t + 256) * 8));
        __syncthreads();
        short8 af[4], bfr[4];
#pragma unroll
        for (int i = 0; i < 4; ++i)
            af[i] = *(const short8*)&As[(wr + i * 16 + lr) * 32 + lq * 8];
#pragma unroll
        for (int j = 0; j < 4; ++j)
            bfr[j] = *(const short8*)&Bs[(wc + j * 16 + lr) * 32 + lq * 8];
#pragma unroll
        for (int i = 0; i < 4; ++i)
#pragma unroll
            for (int j = 0; j < 4; ++j)
                acc[i][j] = mfma16(af[i], bfr[j], acc[i][j]);
        __syncthreads();
    }

    ushort_t* Cw = Cs + wv * 16 * 80;
#pragma unroll
    for (int i = 0; i < 4; ++i) {
#pragma unroll
        for (int j = 0; j < 4; ++j) {
            int colg = n0 + wc + j * 16 + lr;
            float bb = (biasc && colg < N) ? biasc[colg] : 0.f;
#pragma unroll
            for (int r = 0; r < 4; ++r)
                Cw[(lq * 4 + r) * 80 + j * 16 + lr] = f2b(acc[i][j][r] + bb);
        }
        __syncthreads();
#pragma unroll
        for (int rr = 0; rr < 2; ++rr) {
            int c = lane + 64 * rr;
            int row = c >> 3, g8 = c & 7;
            uint4 u = *(const uint4*)&Cw[row * 80 + g8 * 8];
            int colg = n0 + wc + g8 * 8;
            int rowg = m0 + wr + i * 16 + row;
            if (colg < N) *(uint4*)&Cp[(long)rowg * N + colg] = u;
        }
        __syncthreads();
    }
}

__global__ __launch_bounds__(256) void gemm_bt(
    const ushort_t* __restrict__ A, const ushort_t* __restrict__ B,
    ushort_t* __restrict__ C, int N, int K, const float* __restrict__ biasc)
{
    __shared__ ushort_t As[128 * 32], Bs[128 * 32];
    __shared__ __align__(16) ushort_t Cs[4 * 16 * 80];
    tile128(A, B, C, N, K, biasc, blockIdx.y * 128, blockIdx.x * 128, As, Bs, Cs);
}

// z<6:  Fqc[l]   = (Wo_s[l] @ Wq_c[l])^T      = Wq_c_t[l]      @ Wo_sp[l]^T
// z>=6: Fqkv[zz] = (Wo_c[l] @ W{m}_s[l+1])^T  = W{m}_s_t[l+1]  @ Wo_cp[l]^T
__global__ __launch_bounds__(256) void fusew(
    const ushort_t* __restrict__ W8t, const ushort_t* __restrict__ Wo_sp,
    const ushort_t* __restrict__ Wo_cp, ushort_t* __restrict__ Fqc_t,
    ushort_t* __restrict__ Fqkv_t)
{
    __shared__ ushort_t As[128 * 32], Bs[128 * 32];
    __shared__ __align__(16) ushort_t Cs[4 * 16 * 80];
    int z = blockIdx.z;
    const ushort_t *A, *B; ushort_t* C;
    if (z < 6)      { A = W8t + (long)(24 + z) * S2; B = Wo_sp + (long)z * S2; C = Fqc_t + (long)z * S2; }
    else { int zz = z - 6, l = zz / 3, m = zz % 3;
           A = W8t + (long)(m * 6 + l + 1) * S2; B = Wo_cp + (long)l * S2; C = Fqkv_t + (long)zz * S2; }
    tile128(A, B, C, 512, 512, nullptr, blockIdx.y * 128, blockIdx.x * 128, As, Bs, Cs);
}

// ---------------------------------------------------------------------------
// prep: z1 48x[512,512]^T bf16 (vectorized); z2 Wf^T padded (vectorized);
// z3 plain Wo_s/Wo_c bf16; z4 Kin/Vin bf16; z5 embed+PE (fp32 trig, short8);
// z6 gq = g @ Wg_c (fp32). One launch.
// ---------------------------------------------------------------------------
__global__ __launch_bounds__(256) void prep(
    const int* __restrict__ x, const float* __restrict__ emb,
    const float* __restrict__ Wq_s, const float* __restrict__ Wk_s,
    const float* __restrict__ Wv_s, const float* __restrict__ Wo_s,
    const float* __restrict__ Wq_c, const float* __restrict__ Wg_c,
    const float* __restrict__ Wk_c, const float* __restrict__ Wv_c,
    const float* __restrict__ Wo_c, const float* __restrict__ Wf,
    const float* __restrict__ Kin, const float* __restrict__ Vin,
    const float* __restrict__ g,
    ushort_t* __restrict__ W8t, ushort_t* __restrict__ Wf_t,
    ushort_t* __restrict__ Wo_sp, ushort_t* __restrict__ Wo_cp,
    ushort_t* __restrict__ K_bf, ushort_t* __restrict__ V_bf,
    ushort_t* __restrict__ act0, float* __restrict__ gq)
{
    // tile[c][r]: LDS row = output row (n-index), col = k-index.
    // Banks: write phase (scalar, stride 260 dw ≡ 4 mod 32) and read phase
    // (scalar, stride 65 dw ≡ 1 mod 32) are both exactly 2-way = free (m136).
    __shared__ float tile[64][65];
    int bid = blockIdx.x, t = threadIdx.x;
    if (bid < 3072) {
        // 48 x [512,512] fp32 -> transposed bf16
        int mat = bid >> 6, wsel = mat / 6, l = mat % 6;
        const float* src = (wsel == 0) ? Wq_s : (wsel == 1) ? Wk_s : (wsel == 2) ? Wv_s :
                           (wsel == 3) ? Wo_s : (wsel == 4) ? Wq_c : (wsel == 5) ? Wk_c :
                           (wsel == 6) ? Wv_c : Wo_c;
        src += (long)l * S2;
        ushort_t* dst = W8t + (long)mat * S2;
        int within = bid & 63;
        int n0 = (within & 7) * 64, k0 = (within >> 3) * 64;
#pragma unroll
        for (int p = 0; p < 4; ++p) {
            int r = p * 16 + (t >> 4), c4 = (t & 15) * 4;
            float4 v = *(const float4*)(src + (long)(k0 + r) * 512 + n0 + c4);
            tile[c4 + 0][r] = v.x; tile[c4 + 1][r] = v.y;
            tile[c4 + 2][r] = v.z; tile[c4 + 3][r] = v.w;
        }
        __syncthreads();
#pragma unroll
        for (int q = 0; q < 2; ++q) {
            int nl = q * 32 + (t >> 3), k8 = (t & 7) * 8;
            short8 o;
#pragma unroll
            for (int u = 0; u < 8; ++u) o[u] = (short)f2b(tile[nl][k8 + u]);
            *(short8*)(dst + (long)(n0 + nl) * 512 + k0 + k8) = o;
        }
    } else if (bid < 4336) {
        // Wf [512,10000] fp32 -> Wf_t [10112,512] bf16 (transposed, zero-pad)
        int id = bid - 3072;
        int n0 = (id % 158) * 64, k0 = (id / 158) * 64;
#pragma unroll
        for (int p = 0; p < 4; ++p) {
            int r = p * 16 + (t >> 4), c4 = (t & 15) * 4;
            int n = n0 + c4;
            float4 v;
            if (n + 3 < 10000) {
                v = *(const float4*)(Wf + (long)(k0 + r) * 10000 + n);
            } else {
                const float* row = Wf + (long)(k0 + r) * 10000;
                v.x = (n + 0 < 10000) ? row[n + 0] : 0.f;
                v.y = (n + 1 < 10000) ? row[n + 1] : 0.f;
                v.z = (n + 2 < 10000) ? row[n + 2] : 0.f;
                v.w = (n + 3 < 10000) ? row[n + 3] : 0.f;
            }
            tile[c4 + 0][r] = v.x; tile[c4 + 1][r] = v.y;
            tile[c4 + 2][r] = v.z; tile[c4 + 3][r] = v.w;
        }
        __syncthreads();
#pragma unroll
        for (int q = 0; q < 2; ++q) {
            int nl = q * 32 + (t >> 3), k8 = (t & 7) * 8;
            short8 o;
#pragma unroll
            for (int u = 0; u < 8; ++u) o[u] = (short)f2b(tile[nl][k8 + u]);
            *(short8*)(Wf_t + (long)(n0 + nl) * 512 + k0 + k8) = o;
        }
    } else if (bid < 7408) {
        long i = (long)(bid - 4336) * 1024 + t * 4;
        const float* s; ushort_t* o; long off;
        if (i < 6L * S2) { s = Wo_s; o = Wo_sp; off = i; }
        else             { s = Wo_c; o = Wo_cp; off = i - 6L * S2; }
        float4 v = *(const float4*)(s + off);
        ushort4 u; u.x = f2b(v.x); u.y = f2b(v.y); u.z = f2b(v.z); u.w = f2b(v.w);
        *(ushort4*)(o + off) = u;
    } else if (bid < 13680) {
        long i = (long)(bid - 7408) * 1024 + t * 4;
        const float* s; ushort_t* o; long off;
        if (i < 3211264L) { s = Kin; o = K_bf; off = i; }
        else              { s = Vin; o = V_bf; off = i - 3211264L; }
        float4 v = *(const float4*)(s + off);
        ushort4 u; u.x = f2b(v.x); u.y = f2b(v.y); u.z = f2b(v.z); u.w = f2b(v.w);
        *(ushort4*)(o + off) = u;
    } else if (bid < 14192) {
        // embed + positional encoding: 512 blocks x 256 threads x 8 elems.
        // One token per wave; fp32 trig (error ~1e-6 << bf16 quantum 4e-3).
        long i = (long)(bid - 13680) * 2048 + t * 8;
        long tok = i >> 9;
        int d8 = (int)(i & 511);
        int s = (int)(tok & 63);
        int id = x[tok];
        const float* erow = emb + (long)id * 512 + d8;
        float4 e0 = *(const float4*)(erow);
        float4 e1 = *(const float4*)(erow + 4);
        float ev[8] = {e0.x, e0.y, e0.z, e0.w, e1.x, e1.y, e1.z, e1.w};
        int j0 = d8 >> 1;
        float sf = (float)s;
        short8 o;
#pragma unroll
        for (int u = 0; u < 4; ++u) {
            // 10000^(-2j/512) = exp(-(ln 1e4 / 256) * j)
            float invf = expf(-0.035977892f * (float)(j0 + u));
            float ang = sf * invf;
            o[2 * u]     = (short)f2b(ev[2 * u]     + sinf(ang));
            o[2 * u + 1] = (short)f2b(ev[2 * u + 1] + cosf(ang));
        }
        *(short8*)(act0 + i) = o;
    } else {
        __shared__ float gs[512];
        int id = bid - 14192;           // [0,384)
        int lb = id >> 1, half = id & 1;
        int l = lb >> 5, b = lb & 31;
        for (int i = t; i < 512; i += 256) gs[i] = g[b * 512 + i];
        __syncthreads();
        int o = half * 256 + t;
        const float* wcol = Wg_c + (long)l * S2 + o;
        float acc = 0.f;
#pragma unroll 8
        for (int i = 0; i < 512; ++i) acc += gs[i] * wcol[(long)i * 512];
        gq[((long)l * 32 + b) * 512 + o] = acc;
    }
}

// ---------------------------------------------------------------------------
// layer_self: per (b,h): q/k/v = act_b @ W slices (MFMA, W staged in LDS),
// causal attention (MFMA scores + fp32 softmax + MFMA PV), attnout bf16.
// ---------------------------------------------------------------------------
__global__ __launch_bounds__(256, 1) void layer_self(
    const ushort_t* __restrict__ act,
    const ushort_t* __restrict__ Wq, const ushort_t* __restrict__ Wk,
    const ushort_t* __restrict__ Wv, ushort_t* __restrict__ attnout)
{
    __shared__ __align__(16) char smem[111616];
    ushort_t* Wst = (ushort_t*)smem;             // [64][520]
    ushort_t* Qs  = (ushort_t*)(smem + 66560);   // [64][72]  (P after softmax)
    ushort_t* Ks  = (ushort_t*)(smem + 75776);   // [64][72]
    ushort_t* Vt  = (ushort_t*)(smem + 84992);   // [64][72]  (transposed)
    float*    Ss  = (float*)(smem + 94208);      // [64][68]

    int b = blockIdx.x >> 3, h = blockIdx.x & 7;
    int t = threadIdx.x, wv = t >> 6, lane = t & 63;
    int lr = lane & 15, lq = lane >> 4;
    const ushort_t* actb = act + (long)b * 64 * 512;

    for (int mat = 0; mat < 3; ++mat) {
        const ushort_t* W = ((mat == 0) ? Wq : (mat == 1) ? Wk : Wv) + h * 64 * 512;
        __syncthreads();
#pragma unroll
        for (int i = 0; i < 16; ++i) {
            int row = i * 4 + wv;
            glds16(W + row * 512 + lane * 8, Wst + row * 520 + lane * 8);
        }
        __syncthreads();
        f32x4 acc[4];
#pragma unroll
        for (int j = 0; j < 4; ++j) acc[j] = (f32x4){0.f, 0.f, 0.f, 0.f};
        const ushort_t* arow = actb + (wv * 16 + lr) * 512;
#pragma unroll 4
        for (int k = 0; k < 16; ++k) {
            short8 a = *(const short8*)(arow + k * 32 + lq * 8);
#pragma unroll
            for (int j = 0; j < 4; ++j) {
                short8 bb = *(const short8*)&Wst[(j * 16 + lr) * 520 + k * 32 + lq * 8];
                acc[j] = mfma16(a, bb, acc[j]);
            }
        }
        if (mat == 2) {
#pragma unroll
            for (int j = 0; j < 4; ++j)
#pragma unroll
                for (int r = 0; r < 4; ++r)
                    Vt[(j * 16 + lr) * 72 + wv * 16 + lq * 4 + r] = f2b(acc[j][r]);
        } else {
            ushort_t* Dst = (mat == 0) ? Qs : Ks;
#pragma unroll
            for (int j = 0; j < 4; ++j)
#pragma unroll
                for (int r = 0; r < 4; ++r)
                    Dst[(wv * 16 + lq * 4 + r) * 72 + j * 16 + lr] = f2b(acc[j][r]);
        }
    }
    __syncthreads();

    // scores S = Q @ K^T
    f32x4 sc[4];
#pragma unroll
    for (int j = 0; j < 4; ++j) sc[j] = (f32x4){0.f, 0.f, 0.f, 0.f};
#pragma unroll
    for (int k2 = 0; k2 < 2; ++k2) {
        short8 a = *(const short8*)&Qs[(wv * 16 + lr) * 72 + k2 * 32 + lq * 8];
#pragma unroll
        for (int j = 0; j < 4; ++j) {
            short8 bb = *(const short8*)&Ks[(j * 16 + lr) * 72 + k2 * 32 + lq * 8];
            sc[j] = mfma16(a, bb, sc[j]);
        }
    }
#pragma unroll
    for (int j = 0; j < 4; ++j)
#pragma unroll
        for (int r = 0; r < 4; ++r)
            Ss[(wv * 16 + lq * 4 + r) * 68 + j * 16 + lr] = sc[j][r];
    __syncthreads();

    // causal softmax; P (bf16) overwrites Qs
    for (int rr = 0; rr < 16; ++rr) {
        int r = wv * 16 + rr;
        float sv = (lane <= r) ? Ss[r * 68 + lane] * 0.125f : -INFINITY;
        float m = sv;
        for (int off = 32; off; off >>= 1) m = fmaxf(m, __shfl_xor(m, off));
        float p = __expf(sv - m);
        float su = p;
        for (int off = 32; off; off >>= 1) su += __shfl_xor(su, off);
        Qs[r * 72 + lane] = f2b(p / su);
    }
    __syncthreads();

    // O = P @ V  (B operand = Vt[d][key])
    f32x4 ov[4];
#pragma unroll
    for (int j = 0; j < 4; ++j) ov[j] = (f32x4){0.f, 0.f, 0.f, 0.f};
#pragma unroll
    for (int k2 = 0; k2 < 2; ++k2) {
        short8 a = *(const short8*)&Qs[(wv * 16 + lr) * 72 + k2 * 32 + lq * 8];
#pragma unroll
        for (int j = 0; j < 4; ++j) {
            short8 bb = *(const short8*)&Vt[(j * 16 + lr) * 72 + k2 * 32 + lq * 8];
            ov[j] = mfma16(a, bb, ov[j]);
        }
    }
    long obase = ((long)b * 64) * 512 + h * 64;
#pragma unroll
    for (int j = 0; j < 4; ++j)
#pragma unroll
        for (int r = 0; r < 4; ++r)
            attnout[obase + (long)(wv * 16 + lq * 4 + r) * 512 + j * 16 + lr] = f2b(ov[j][r]);
}

// ---------------------------------------------------------------------------
// layer_cross: per (b,h): qc = attnout_b @ Fqc + gq; kc/vc = K_b/V_b @ W
// slices (in-kernel, 208-row padded); scores+softmax+PV via MFMA.
// ---------------------------------------------------------------------------
__global__ __launch_bounds__(256, 1) void layer_cross(
    const ushort_t* __restrict__ attnout, const ushort_t* __restrict__ Kb,
    const ushort_t* __restrict__ Vb, const ushort_t* __restrict__ Fqc,
    const ushort_t* __restrict__ Wkc, const ushort_t* __restrict__ Wvc,
    const float* __restrict__ gql, ushort_t* __restrict__ crossout)
{
    __shared__ __align__(16) char smem[134400];
    ushort_t* Wst = (ushort_t*)smem;             // [64][520] weight stage
    float*    Ss  = (float*)smem;                // [64][216] scores (after weights dead)
    ushort_t* Qs  = (ushort_t*)(smem + 66560);   // [64][72]
    ushort_t* Kc  = (ushort_t*)(smem + 75776);   // [208][72]; Pb [64][224] after
    ushort_t* Pb  = Kc;
    ushort_t* Vt  = (ushort_t*)(smem + 105728);  // [64][224]

    int b = blockIdx.x >> 3, h = blockIdx.x & 7;
    int t = threadIdx.x, wv = t >> 6, lane = t & 63;
    int lr = lane & 15, lq = lane >> 4;
    const ushort_t* atb = attnout + (long)b * 64 * 512;
    const ushort_t* Kbb = Kb + (long)b * 196 * 512;
    const ushort_t* Vbb = Vb + (long)b * 196 * 512;

    // Phase A: qc
    {
        const ushort_t* W = Fqc + h * 64 * 512;
#pragma unroll
        for (int i = 0; i < 16; ++i) {
            int row = i * 4 + wv;
            glds16(W + row * 512 + lane * 8, Wst + row * 520 + lane * 8);
        }
        __syncthreads();
        f32x4 acc[4];
#pragma unroll
        for (int j = 0; j < 4; ++j) acc[j] = (f32x4){0.f, 0.f, 0.f, 0.f};
        const ushort_t* arow = atb + (wv * 16 + lr) * 512;
#pragma unroll 4
        for (int k = 0; k < 16; ++k) {
            short8 a = *(const short8*)(arow + k * 32 + lq * 8);
#pragma unroll
            for (int j = 0; j < 4; ++j) {
                short8 bb = *(const short8*)&Wst[(j * 16 + lr) * 520 + k * 32 + lq * 8];
                acc[j] = mfma16(a, bb, acc[j]);
            }
        }
#pragma unroll
        for (int j = 0; j < 4; ++j)
#pragma unroll
            for (int r = 0; r < 4; ++r) {
                int col = j * 16 + lr;
                Qs[(wv * 16 + lq * 4 + r) * 72 + col] =
                    f2b(acc[j][r] + gql[b * 512 + h * 64 + col]);
            }
    }
    // Phase B: kc then vc (rows padded to 208; garbage rows masked downstream)
#pragma unroll
    for (int mat = 0; mat < 2; ++mat) {
        const ushort_t* W = ((mat == 0) ? Wkc : Wvc) + h * 64 * 512;
        const ushort_t* Src = (mat == 0) ? Kbb : Vbb;
        __syncthreads();
#pragma unroll
        for (int i = 0; i < 16; ++i) {
            int row = i * 4 + wv;
            glds16(W + row * 512 + lane * 8, Wst + row * 520 + lane * 8);
        }
        __syncthreads();
        for (int rt = wv; rt < 13; rt += 4) {
            f32x4 acc[4];
#pragma unroll
            for (int j = 0; j < 4; ++j) acc[j] = (f32x4){0.f, 0.f, 0.f, 0.f};
            const ushort_t* arow = Src + (long)(rt * 16 + lr) * 512;
#pragma unroll 4
            for (int k = 0; k < 16; ++k) {
                short8 a = *(const short8*)(arow + k * 32 + lq * 8);
#pragma unroll
                for (int j = 0; j < 4; ++j) {
                    short8 bb = *(const short8*)&Wst[(j * 16 + lr) * 520 + k * 32 + lq * 8];
                    acc[j] = mfma16(a, bb, acc[j]);
                }
            }
            if (mat == 0) {
#pragma unroll
                for (int j = 0; j < 4; ++j)
#pragma unroll
                    for (int r = 0; r < 4; ++r)
                        Kc[(rt * 16 + lq * 4 + r) * 72 + j * 16 + lr] = f2b(acc[j][r]);
            } else {
#pragma unroll
                for (int j = 0; j < 4; ++j)
#pragma unroll
                    for (int r = 0; r < 4; ++r)
                        Vt[(j * 16 + lr) * 224 + rt * 16 + lq * 4 + r] = f2b(acc[j][r]);
            }
        }
    }
    __syncthreads();
    // zero Vt pad cols 196..223 (kill garbage incl. NaN before PV MFMA)
    for (int e = t; e < 64 * 28; e += 256) Vt[(e / 28) * 224 + 196 + (e % 28)] = 0;

    // Phase C: S = Qc @ Kc^T  (64 x 208)
    f32x4 sc[13];
#pragma unroll
    for (int ct = 0; ct < 13; ++ct) sc[ct] = (f32x4){0.f, 0.f, 0.f, 0.f};
#pragma unroll
    for (int k2 = 0; k2 < 2; ++k2) {
        short8 a = *(const short8*)&Qs[(wv * 16 + lr) * 72 + k2 * 32 + lq * 8];
#pragma unroll
        for (int ct = 0; ct < 13; ++ct) {
            short8 bb = *(const short8*)&Kc[(ct * 16 + lr) * 72 + k2 * 32 + lq * 8];
            sc[ct] = mfma16(a, bb, sc[ct]);
        }
    }
#pragma unroll
    for (int ct = 0; ct < 13; ++ct)
#pragma unroll
        for (int r = 0; r < 4; ++r)
            Ss[(wv * 16 + lq * 4 + r) * 216 + ct * 16 + lr] = sc[ct][r];
    __syncthreads();

    // Phase D: softmax over 196 cols; P bf16 into Kc region (+zero pad cols)
    for (int rr = 0; rr < 16; ++rr) {
        int r = wv * 16 + rr;
        float v0 = Ss[r * 216 + lane] * 0.125f;
        float v1 = Ss[r * 216 + 64 + lane] * 0.125f;
        float v2 = Ss[r * 216 + 128 + lane] * 0.125f;
        float v3 = (lane < 4) ? Ss[r * 216 + 192 + lane] * 0.125f : -INFINITY;
        float m = fmaxf(fmaxf(v0, v1), fmaxf(v2, v3));
        for (int off = 32; off; off >>= 1) m = fmaxf(m, __shfl_xor(m, off));
        float e0 = __expf(v0 - m), e1 = __expf(v1 - m), e2 = __expf(v2 - m);
        float e3 = (lane < 4) ? __expf(v3 - m) : 0.f;
        float su = e0 + e1 + e2 + e3;
        for (int off = 32; off; off >>= 1) su += __shfl_xor(su, off);
        float inv = 1.f / su;
        Pb[r * 224 + lane]       = f2b(e0 * inv);
        Pb[r * 224 + 64 + lane]  = f2b(e1 * inv);
        Pb[r * 224 + 128 + lane] = f2b(e2 * inv);
        if (lane < 4)  Pb[r * 224 + 192 + lane] = f2b(e3 * inv);
        if (lane < 28) Pb[r * 224 + 196 + lane] = 0;
    }
    __syncthreads();

    // Phase E: O = P @ Vc  (K = 224)
    f32x4 ov[4];
#pragma unroll
    for (int j = 0; j < 4; ++j) ov[j] = (f32x4){0.f, 0.f, 0.f, 0.f};
#pragma unroll
    for (int k2 = 0; k2 < 7; ++k2) {
        short8 a = *(const short8*)&Pb[(wv * 16 + lr) * 224 + k2 * 32 + lq * 8];
#pragma unroll
        for (int j = 0; j < 4; ++j) {
            short8 bb = *(const short8*)&Vt[(j * 16 + lr) * 224 + k2 * 32 + lq * 8];
            ov[j] = mfma16(a, bb, ov[j]);
        }
    }
    long obase = ((long)b * 64) * 512 + h * 64;
#pragma unroll
    for (int j = 0; j < 4; ++j)
#pragma unroll
        for (int r = 0; r < 4; ++r)
            crossout[obase + (long)(wv * 16 + lq * 4 + r) * 512 + j * 16 + lr] = f2b(ov[j][r]);
}

// ---------------------------------------------------------------------------
// Softmax over bf16 logits -> fp32 probs. One block per row.
// ---------------------------------------------------------------------------
__global__ __launch_bounds__(256) void softmax_bf(const ushort_t* __restrict__ lg,
                                                  float* __restrict__ out)
{
    __shared__ float red[8];
    long row = blockIdx.x;
    const ushort_t* p = lg + row * 10000L;
    float* po = out + row * 10000L;
    int t = threadIdx.x;
    int w = t >> 6, lane = t & 63;
    float vals[40];
    float mx = -INFINITY;
#pragma unroll
    for (int ii = 0; ii < 40; ++ii) {
        int c = t + (ii << 8);
        if (c < 10000) { float v = b2f(p[c]); vals[ii] = v; mx = fmaxf(mx, v); }
        else vals[ii] = -INFINITY;
    }
    for (int off = 32; off; off >>= 1) mx = fmaxf(mx, __shfl_xor(mx, off));
    if (lane == 0) red[w] = mx;
    __syncthreads();
    mx = fmaxf(fmaxf(red[0], red[1]), fmaxf(red[2], red[3]));
    float s = 0.f;
#pragma unroll
    for (int ii = 0; ii < 40; ++ii) {
        float e = __expf(vals[ii] - mx);
        vals[ii] = e;
        s += e;
    }
    for (int off = 32; off; off >>= 1) s += __shfl_xor(s, off);
    if (lane == 0) red[4 + w] = s;
    __syncthreads();
    s = red[4] + red[5] + red[6] + red[7];
    float inv = 1.0f / s;
#pragma unroll
    for (int ii = 0; ii < 40; ++ii) {
        int c = t + (ii << 8);
        if (c < 10000) po[c] = vals[ii] * inv;
    }
}

// ---------------------------------------------------------------------------
extern "C" void kernel_launch(void* const* d_in, const int* in_sizes, int n_in,
                              void* d_out, int out_size, void* d_ws, size_t ws_size,
                              hipStream_t stream)
{
    const int*   x    = (const int*)d_in[0];
    const float* Kin  = (const float*)d_in[1];
    const float* Vin  = (const float*)d_in[2];
    const float* g    = (const float*)d_in[3];
    const float* emb  = (const float*)d_in[5];
    const float* Wq_s = (const float*)d_in[6];
    const float* Wk_s = (const float*)d_in[7];
    const float* Wv_s = (const float*)d_in[8];
    const float* Wo_s = (const float*)d_in[9];
    const float* Wq_c = (const float*)d_in[10];
    const float* Wg_c = (const float*)d_in[11];
    const float* Wk_c = (const float*)d_in[12];
    const float* Wv_c = (const float*)d_in[13];
    const float* Wo_c = (const float*)d_in[14];
    const float* Wf   = (const float*)d_in[15];
    const float* bf   = (const float*)d_in[16];
    float* out = (float*)d_out;

    float* gq = (float*)d_ws;                                // [6,32,512] fp32
    ushort_t* act0     = (ushort_t*)(gq + 98304);            // [2048,512]
    ushort_t* crossout = act0 + 1048576;
    ushort_t* attnout  = crossout + 1048576;
    ushort_t* K_bf     = attnout + 1048576;                  // [6272,512]
    ushort_t* V_bf     = K_bf + 3211264;
    ushort_t* W8t      = V_bf + 3211264;                     // 48 x [512,512]^T
    ushort_t* Wf_t     = W8t + 48L * S2;                     // [10112,512]
    ushort_t* Wo_sp    = Wf_t + 5177344;                     // 6 x plain
    ushort_t* Wo_cp    = Wo_sp + 6L * S2;                    // 6 x plain
    ushort_t* Fqc_t    = Wo_cp + 6L * S2;                    // 6 x [512,512]
    ushort_t* Fqkv_t   = Fqc_t + 6L * S2;                    // 15 x [512,512]
    ushort_t* Wfin_t   = Fqkv_t + 15L * S2;                  // [10112,512]
    ushort_t* logits   = W8t;                                // reuse after layers

    prep<<<14576, 256, 0, stream>>>(x, emb, Wq_s, Wk_s, Wv_s, Wo_s, Wq_c, Wg_c,
                                    Wk_c, Wv_c, Wo_c, Wf, Kin, Vin, g,
                                    W8t, Wf_t, Wo_sp, Wo_cp, K_bf, V_bf, act0, gq);
    fusew<<<dim3(4, 4, 21), 256, 0, stream>>>(W8t, Wo_sp, Wo_cp, Fqc_t, Fqkv_t);
    // Wfin = (Wo_c[5] @ Wf)^T = Wf_t @ Wo_cp[5]^T  -> [10112,512]
    gemm_bt<<<dim3(4, 79, 1), 256, 0, stream>>>(Wf_t, Wo_cp + 5L * S2, Wfin_t,
                                                512, 512, nullptr);

    for (int l = 0; l < 6; ++l) {
        const ushort_t *A, *Bq, *Bk, *Bv;
        if (l == 0) {
            A = act0;
            Bq = W8t + 0L * 6 * S2; Bk = W8t + 1L * 6 * S2; Bv = W8t + 2L * 6 * S2;
        } else {
            A = crossout;
            Bq = Fqkv_t + (long)((l - 1) * 3) * S2;
            Bk = Bq + S2; Bv = Bq + 2 * S2;
        }
        layer_self<<<256, 256, 0, stream>>>(A, Bq, Bk, Bv, attnout);
        layer_cross<<<256, 256, 0, stream>>>(attnout, K_bf, V_bf,
                                             Fqc_t + (long)l * S2,
                                             W8t + (long)(5 * 6 + l) * S2,
                                             W8t + (long)(6 * 6 + l) * S2,
                                             gq + (long)l * 16384, crossout);
    }

    gemm_bt<<<dim3(79, 16, 1), 256, 0, stream>>>(crossout, Wfin_t, logits,
                                                 10000, 512, bf);
    softmax_bf<<<2048, 256, 0, stream>>>(logits, out);
}

// Round 3
// 739.899 us; speedup vs baseline: 1.0047x; 1.0047x over previous
//
#include <hip/hip_runtime.h>
#include <math.h>

// GlobalAdaptiveDecoder: B=32 S=64 D=512 H=8 DK=DV=64 NR=196 L=6 VOCAB=10000
// Round 6: prep restructured for memory-level parallelism (latency-bound fix):
// 2 tiles/block transposes (8 float4 in flight), K/V convert 8 float4/thread,
// plain-Wo conversion fused into the transpose pass (removes 12 MB re-read).
// Grid 14576 -> 3848 blocks. 17 launches.

#define S2 (512*512)
typedef unsigned short ushort_t;
typedef unsigned int u32;
typedef __attribute__((ext_vector_type(8))) short short8;
typedef __attribute__((ext_vector_type(4))) float f32x4;

__device__ __forceinline__ ushort_t f2b(float f) {
    union { float f; u32 u; } v; v.f = f;
    u32 r = (v.u + 0x7fffu + ((v.u >> 16) & 1u)) >> 16;
    return (ushort_t)r;
}
__device__ __forceinline__ float b2f(ushort_t u) {
    union { u32 u; float f; } v; v.u = ((u32)u) << 16; return v.f;
}
__device__ __forceinline__ void glds16(const void* g, void* l) {
    __builtin_amdgcn_global_load_lds((const __attribute__((address_space(1))) u32*)g,
                                     (__attribute__((address_space(3))) u32*)l,
                                     16, 0, 0);
}
__device__ __forceinline__ f32x4 mfma16(short8 a, short8 b, f32x4 c) {
    return __builtin_amdgcn_mfma_f32_16x16x32_bf16(a, b, c, 0, 0, 0);
}

// ---------------------------------------------------------------------------
// 128x128 MFMA tile body (shared by gemm_bt / fusew). C = A @ B^T (+bias),
// bf16 out via LDS-coalesced epilogue. Rows covered by grid; N mult of 8.
// ---------------------------------------------------------------------------
__device__ __forceinline__ void tile128(
    const ushort_t* __restrict__ A, const ushort_t* __restrict__ B,
    ushort_t* __restrict__ Cp, int N, int K, const float* __restrict__ biasc,
    int m0, int n0, ushort_t* As, ushort_t* Bs, ushort_t* Cs)
{
    int t = threadIdx.x;
    int sr = t >> 2, sk = (t & 3) * 8;
    int wv = t >> 6, lane = t & 63;
    int wr = (wv >> 1) * 64, wc = (wv & 1) * 64;
    int lr = lane & 15, lq = lane >> 4;

    f32x4 acc[4][4];
#pragma unroll
    for (int i = 0; i < 4; ++i)
#pragma unroll
        for (int j = 0; j < 4; ++j) acc[i][j] = (f32x4){0.f, 0.f, 0.f, 0.f};

    for (int k0 = 0; k0 < K; k0 += 32) {
        glds16(A + (long)(m0 + sr) * K + k0 + sk,      (void*)(As + t * 8));
        glds16(A + (long)(m0 + sr + 64) * K + k0 + sk, (void*)(As + (t + 256) * 8));
        glds16(B + (long)(n0 + sr) * K + k0 + sk,      (void*)(Bs + t * 8));
        glds16(B + (long)(n0 + sr + 64) * K + k0 + sk, (void*)(Bs + (t + 256) * 8));
        __syncthreads();
        short8 af[4], bfr[4];
#pragma unroll
        for (int i = 0; i < 4; ++i)
            af[i] = *(const short8*)&As[(wr + i * 16 + lr) * 32 + lq * 8];
#pragma unroll
        for (int j = 0; j < 4; ++j)
            bfr[j] = *(const short8*)&Bs[(wc + j * 16 + lr) * 32 + lq * 8];
#pragma unroll
        for (int i = 0; i < 4; ++i)
#pragma unroll
            for (int j = 0; j < 4; ++j)
                acc[i][j] = mfma16(af[i], bfr[j], acc[i][j]);
        __syncthreads();
    }

    ushort_t* Cw = Cs + wv * 16 * 80;
#pragma unroll
    for (int i = 0; i < 4; ++i) {
#pragma unroll
        for (int j = 0; j < 4; ++j) {
            int colg = n0 + wc + j * 16 + lr;
            float bb = (biasc && colg < N) ? biasc[colg] : 0.f;
#pragma unroll
            for (int r = 0; r < 4; ++r)
                Cw[(lq * 4 + r) * 80 + j * 16 + lr] = f2b(acc[i][j][r] + bb);
        }
        __syncthreads();
#pragma unroll
        for (int rr = 0; rr < 2; ++rr) {
            int c = lane + 64 * rr;
            int row = c >> 3, g8 = c & 7;
            uint4 u = *(const uint4*)&Cw[row * 80 + g8 * 8];
            int colg = n0 + wc + g8 * 8;
            int rowg = m0 + wr + i * 16 + row;
            if (colg < N) *(uint4*)&Cp[(long)rowg * N + colg] = u;
        }
        __syncthreads();
    }
}

__global__ __launch_bounds__(256) void gemm_bt(
    const ushort_t* __restrict__ A, const ushort_t* __restrict__ B,
    ushort_t* __restrict__ C, int N, int K, const float* __restrict__ biasc)
{
    __shared__ ushort_t As[128 * 32], Bs[128 * 32];
    __shared__ __align__(16) ushort_t Cs[4 * 16 * 80];
    tile128(A, B, C, N, K, biasc, blockIdx.y * 128, blockIdx.x * 128, As, Bs, Cs);
}

// z<6:  Fqc[l]   = (Wo_s[l] @ Wq_c[l])^T      = Wq_c_t[l]      @ Wo_sp[l]^T
// z>=6: Fqkv[zz] = (Wo_c[l] @ W{m}_s[l+1])^T  = W{m}_s_t[l+1]  @ Wo_cp[l]^T
__global__ __launch_bounds__(256) void fusew(
    const ushort_t* __restrict__ W8t, const ushort_t* __restrict__ Wo_sp,
    const ushort_t* __restrict__ Wo_cp, ushort_t* __restrict__ Fqc_t,
    ushort_t* __restrict__ Fqkv_t)
{
    __shared__ ushort_t As[128 * 32], Bs[128 * 32];
    __shared__ __align__(16) ushort_t Cs[4 * 16 * 80];
    int z = blockIdx.z;
    const ushort_t *A, *B; ushort_t* C;
    if (z < 6)      { A = W8t + (long)(24 + z) * S2; B = Wo_sp + (long)z * S2; C = Fqc_t + (long)z * S2; }
    else { int zz = z - 6, l = zz / 3, m = zz % 3;
           A = W8t + (long)(m * 6 + l + 1) * S2; B = Wo_cp + (long)l * S2; C = Fqkv_t + (long)zz * S2; }
    tile128(A, B, C, 512, 512, nullptr, blockIdx.y * 128, blockIdx.x * 128, As, Bs, Cs);
}

// ---------------------------------------------------------------------------
// prep (ILP-8 restructure):
//  [0,1536)    48x[512,512]^T bf16, 2 tiles/block; plain Wo_sp/Wo_cp fused
//  [1536,2168) Wf^T padded, 2 tiles/block
//  [2168,2952) K/V fp32->bf16, 8 float4/thread
//  [2952,3464) embed+PE (fp32 trig, short8)
//  [3464,3848) gq = g @ Wg_c (fp32)
// ---------------------------------------------------------------------------
__global__ __launch_bounds__(256) void prep(
    const int* __restrict__ x, const float* __restrict__ emb,
    const float* __restrict__ Wq_s, const float* __restrict__ Wk_s,
    const float* __restrict__ Wv_s, const float* __restrict__ Wo_s,
    const float* __restrict__ Wq_c, const float* __restrict__ Wg_c,
    const float* __restrict__ Wk_c, const float* __restrict__ Wv_c,
    const float* __restrict__ Wo_c, const float* __restrict__ Wf,
    const float* __restrict__ Kin, const float* __restrict__ Vin,
    const float* __restrict__ g,
    ushort_t* __restrict__ W8t, ushort_t* __restrict__ Wf_t,
    ushort_t* __restrict__ Wo_sp, ushort_t* __restrict__ Wo_cp,
    ushort_t* __restrict__ K_bf, ushort_t* __restrict__ V_bf,
    ushort_t* __restrict__ act0, float* __restrict__ gq)
{
    // tile[h][c][r]: two 64x64 tiles. Write phase bank = (c + r) mod 32
    // (65 dw stride), read phase bank = (nl + 8*(t&3) + u) mod 32 — both
    // exactly 2-way across a wave = free (m136).
    __shared__ float tile[2][64][65];
    int bid = blockIdx.x, t = threadIdx.x;
    if (bid < 1536) {
        // 48 x [512,512] fp32 -> transposed bf16 (+ plain bf16 for Wo_s/Wo_c)
        int mat = bid >> 5, wsel = mat / 6, l = mat % 6;
        const float* src = (wsel == 0) ? Wq_s : (wsel == 1) ? Wk_s : (wsel == 2) ? Wv_s :
                           (wsel == 3) ? Wo_s : (wsel == 4) ? Wq_c : (wsel == 5) ? Wk_c :
                           (wsel == 6) ? Wv_c : Wo_c;
        src += (long)l * S2;
        ushort_t* dst = W8t + (long)mat * S2;
        ushort_t* plain = (wsel == 3) ? Wo_sp + (long)l * S2
                        : (wsel == 7) ? Wo_cp + (long)l * S2 : nullptr;
        int within = bid & 31;
        int n0 = (within & 7) * 64, kb = (within >> 3) * 128;
        int r0 = t >> 4, c4 = (t & 15) * 4;
        float4 v[2][4];
#pragma unroll
        for (int h2 = 0; h2 < 2; ++h2)
#pragma unroll
            for (int p = 0; p < 4; ++p)
                v[h2][p] = *(const float4*)(src + (long)(kb + h2 * 64 + p * 16 + r0) * 512 + n0 + c4);
#pragma unroll
        for (int h2 = 0; h2 < 2; ++h2)
#pragma unroll
            for (int p = 0; p < 4; ++p) {
                int r = p * 16 + r0;
                tile[h2][c4 + 0][r] = v[h2][p].x; tile[h2][c4 + 1][r] = v[h2][p].y;
                tile[h2][c4 + 2][r] = v[h2][p].z; tile[h2][c4 + 3][r] = v[h2][p].w;
            }
        if (plain) {
#pragma unroll
            for (int h2 = 0; h2 < 2; ++h2)
#pragma unroll
                for (int p = 0; p < 4; ++p) {
                    ushort4 w;
                    w.x = f2b(v[h2][p].x); w.y = f2b(v[h2][p].y);
                    w.z = f2b(v[h2][p].z); w.w = f2b(v[h2][p].w);
                    *(ushort4*)(plain + (long)(kb + h2 * 64 + p * 16 + r0) * 512 + n0 + c4) = w;
                }
        }
        __syncthreads();
#pragma unroll
        for (int h2 = 0; h2 < 2; ++h2)
#pragma unroll
            for (int q = 0; q < 2; ++q) {
                int nl = q * 32 + (t >> 3), k8 = (t & 7) * 8;
                short8 o;
#pragma unroll
                for (int u = 0; u < 8; ++u) o[u] = (short)f2b(tile[h2][nl][k8 + u]);
                *(short8*)(dst + (long)(n0 + nl) * 512 + kb + h2 * 64 + k8) = o;
            }
    } else if (bid < 2168) {
        // Wf [512,10000] fp32 -> Wf_t [10112,512] bf16, 2 k-tiles/block
        int id = bid - 1536;
        int n0 = (id % 158) * 64, kb = (id / 158) * 128;
        int r0 = t >> 4, c4 = (t & 15) * 4;
        int n = n0 + c4;
        float4 v[2][4];
#pragma unroll
        for (int h2 = 0; h2 < 2; ++h2)
#pragma unroll
            for (int p = 0; p < 4; ++p) {
                const float* row = Wf + (long)(kb + h2 * 64 + p * 16 + r0) * 10000;
                float4 w;
                if (n + 3 < 10000) {
                    w = *(const float4*)(row + n);
                } else {
                    w.x = (n + 0 < 10000) ? row[n + 0] : 0.f;
                    w.y = (n + 1 < 10000) ? row[n + 1] : 0.f;
                    w.z = (n + 2 < 10000) ? row[n + 2] : 0.f;
                    w.w = (n + 3 < 10000) ? row[n + 3] : 0.f;
                }
                v[h2][p] = w;
            }
#pragma unroll
        for (int h2 = 0; h2 < 2; ++h2)
#pragma unroll
            for (int p = 0; p < 4; ++p) {
                int r = p * 16 + r0;
                tile[h2][c4 + 0][r] = v[h2][p].x; tile[h2][c4 + 1][r] = v[h2][p].y;
                tile[h2][c4 + 2][r] = v[h2][p].z; tile[h2][c4 + 3][r] = v[h2][p].w;
            }
        __syncthreads();
#pragma unroll
        for (int h2 = 0; h2 < 2; ++h2)
#pragma unroll
            for (int q = 0; q < 2; ++q) {
                int nl = q * 32 + (t >> 3), k8 = (t & 7) * 8;
                short8 o;
#pragma unroll
                for (int u = 0; u < 8; ++u) o[u] = (short)f2b(tile[h2][nl][k8 + u]);
                *(short8*)(Wf_t + (long)(n0 + nl) * 512 + kb + h2 * 64 + k8) = o;
            }
    } else if (bid < 2952) {
        // K/V fp32 -> bf16: 8 float4 loads in flight per thread
        int sec = bid - 2168;               // [0,784)
        const float* s; ushort_t* o; long fbase;
        if (sec < 392) { s = Kin; o = K_bf; fbase = (long)sec * 2048; }
        else           { s = Vin; o = V_bf; fbase = (long)(sec - 392) * 2048; }
        float4 v[8];
#pragma unroll
        for (int u = 0; u < 8; ++u)
            v[u] = *(const float4*)(s + 4 * (fbase + t + 256 * u));
#pragma unroll
        for (int u = 0; u < 8; ++u) {
            long fi = fbase + t + 256 * u;
            ushort4 w;
            w.x = f2b(v[u].x); w.y = f2b(v[u].y); w.z = f2b(v[u].z); w.w = f2b(v[u].w);
            *(ushort4*)(o + 4 * fi) = w;
        }
    } else if (bid < 3464) {
        // embed + positional encoding: fp32 trig (err ~1e-6 << bf16 quantum)
        long i = (long)(bid - 2952) * 2048 + t * 8;
        long tok = i >> 9;
        int d8 = (int)(i & 511);
        int s = (int)(tok & 63);
        int id = x[tok];
        const float* erow = emb + (long)id * 512 + d8;
        float4 e0 = *(const float4*)(erow);
        float4 e1 = *(const float4*)(erow + 4);
        float ev[8] = {e0.x, e0.y, e0.z, e0.w, e1.x, e1.y, e1.z, e1.w};
        int j0 = d8 >> 1;
        float sf = (float)s;
        short8 o;
#pragma unroll
        for (int u = 0; u < 4; ++u) {
            // 10000^(-2j/512) = exp(-(ln 1e4 / 256) * j)
            float invf = expf(-0.035977892f * (float)(j0 + u));
            float ang = sf * invf;
            o[2 * u]     = (short)f2b(ev[2 * u]     + sinf(ang));
            o[2 * u + 1] = (short)f2b(ev[2 * u + 1] + cosf(ang));
        }
        *(short8*)(act0 + i) = o;
    } else {
        __shared__ float gs[512];
        int id = bid - 3464;            // [0,384)
        int lb = id >> 1, half = id & 1;
        int l = lb >> 5, b = lb & 31;
        for (int i = t; i < 512; i += 256) gs[i] = g[b * 512 + i];
        __syncthreads();
        int o = half * 256 + t;
        const float* wcol = Wg_c + (long)l * S2 + o;
        float acc = 0.f;
#pragma unroll 8
        for (int i = 0; i < 512; ++i) acc += gs[i] * wcol[(long)i * 512];
        gq[((long)l * 32 + b) * 512 + o] = acc;
    }
}

// ---------------------------------------------------------------------------
// layer_self: per (b,h): q/k/v = act_b @ W slices (MFMA, W staged in LDS),
// causal attention (MFMA scores + fp32 softmax + MFMA PV), attnout bf16.
// ---------------------------------------------------------------------------
__global__ __launch_bounds__(256, 1) void layer_self(
    const ushort_t* __restrict__ act,
    const ushort_t* __restrict__ Wq, const ushort_t* __restrict__ Wk,
    const ushort_t* __restrict__ Wv, ushort_t* __restrict__ attnout)
{
    __shared__ __align__(16) char smem[111616];
    ushort_t* Wst = (ushort_t*)smem;             // [64][520]
    ushort_t* Qs  = (ushort_t*)(smem + 66560);   // [64][72]  (P after softmax)
    ushort_t* Ks  = (ushort_t*)(smem + 75776);   // [64][72]
    ushort_t* Vt  = (ushort_t*)(smem + 84992);   // [64][72]  (transposed)
    float*    Ss  = (float*)(smem + 94208);      // [64][68]

    int b = blockIdx.x >> 3, h = blockIdx.x & 7;
    int t = threadIdx.x, wv = t >> 6, lane = t & 63;
    int lr = lane & 15, lq = lane >> 4;
    const ushort_t* actb = act + (long)b * 64 * 512;

    for (int mat = 0; mat < 3; ++mat) {
        const ushort_t* W = ((mat == 0) ? Wq : (mat == 1) ? Wk : Wv) + h * 64 * 512;
        __syncthreads();
#pragma unroll
        for (int i = 0; i < 16; ++i) {
            int row = i * 4 + wv;
            glds16(W + row * 512 + lane * 8, Wst + row * 520 + lane * 8);
        }
        __syncthreads();
        f32x4 acc[4];
#pragma unroll
        for (int j = 0; j < 4; ++j) acc[j] = (f32x4){0.f, 0.f, 0.f, 0.f};
        const ushort_t* arow = actb + (wv * 16 + lr) * 512;
#pragma unroll 4
        for (int k = 0; k < 16; ++k) {
            short8 a = *(const short8*)(arow + k * 32 + lq * 8);
#pragma unroll
            for (int j = 0; j < 4; ++j) {
                short8 bb = *(const short8*)&Wst[(j * 16 + lr) * 520 + k * 32 + lq * 8];
                acc[j] = mfma16(a, bb, acc[j]);
            }
        }
        if (mat == 2) {
#pragma unroll
            for (int j = 0; j < 4; ++j)
#pragma unroll
                for (int r = 0; r < 4; ++r)
                    Vt[(j * 16 + lr) * 72 + wv * 16 + lq * 4 + r] = f2b(acc[j][r]);
        } else {
            ushort_t* Dst = (mat == 0) ? Qs : Ks;
#pragma unroll
            for (int j = 0; j < 4; ++j)
#pragma unroll
                for (int r = 0; r < 4; ++r)
                    Dst[(wv * 16 + lq * 4 + r) * 72 + j * 16 + lr] = f2b(acc[j][r]);
        }
    }
    __syncthreads();

    // scores S = Q @ K^T
    f32x4 sc[4];
#pragma unroll
    for (int j = 0; j < 4; ++j) sc[j] = (f32x4){0.f, 0.f, 0.f, 0.f};
#pragma unroll
    for (int k2 = 0; k2 < 2; ++k2) {
        short8 a = *(const short8*)&Qs[(wv * 16 + lr) * 72 + k2 * 32 + lq * 8];
#pragma unroll
        for (int j = 0; j < 4; ++j) {
            short8 bb = *(const short8*)&Ks[(j * 16 + lr) * 72 + k2 * 32 + lq * 8];
            sc[j] = mfma16(a, bb, sc[j]);
        }
    }
#pragma unroll
    for (int j = 0; j < 4; ++j)
#pragma unroll
        for (int r = 0; r < 4; ++r)
            Ss[(wv * 16 + lq * 4 + r) * 68 + j * 16 + lr] = sc[j][r];
    __syncthreads();

    // causal softmax; P (bf16) overwrites Qs
    for (int rr = 0; rr < 16; ++rr) {
        int r = wv * 16 + rr;
        float sv = (lane <= r) ? Ss[r * 68 + lane] * 0.125f : -INFINITY;
        float m = sv;
        for (int off = 32; off; off >>= 1) m = fmaxf(m, __shfl_xor(m, off));
        float p = __expf(sv - m);
        float su = p;
        for (int off = 32; off; off >>= 1) su += __shfl_xor(su, off);
        Qs[r * 72 + lane] = f2b(p / su);
    }
    __syncthreads();

    // O = P @ V  (B operand = Vt[d][key])
    f32x4 ov[4];
#pragma unroll
    for (int j = 0; j < 4; ++j) ov[j] = (f32x4){0.f, 0.f, 0.f, 0.f};
#pragma unroll
    for (int k2 = 0; k2 < 2; ++k2) {
        short8 a = *(const short8*)&Qs[(wv * 16 + lr) * 72 + k2 * 32 + lq * 8];
#pragma unroll
        for (int j = 0; j < 4; ++j) {
            short8 bb = *(const short8*)&Vt[(j * 16 + lr) * 72 + k2 * 32 + lq * 8];
            ov[j] = mfma16(a, bb, ov[j]);
        }
    }
    long obase = ((long)b * 64) * 512 + h * 64;
#pragma unroll
    for (int j = 0; j < 4; ++j)
#pragma unroll
        for (int r = 0; r < 4; ++r)
            attnout[obase + (long)(wv * 16 + lq * 4 + r) * 512 + j * 16 + lr] = f2b(ov[j][r]);
}

// ---------------------------------------------------------------------------
// layer_cross: per (b,h): qc = attnout_b @ Fqc + gq; kc/vc = K_b/V_b @ W
// slices (in-kernel, 208-row padded); scores+softmax+PV via MFMA.
// ---------------------------------------------------------------------------
__global__ __launch_bounds__(256, 1) void layer_cross(
    const ushort_t* __restrict__ attnout, const ushort_t* __restrict__ Kb,
    const ushort_t* __restrict__ Vb, const ushort_t* __restrict__ Fqc,
    const ushort_t* __restrict__ Wkc, const ushort_t* __restrict__ Wvc,
    const float* __restrict__ gql, ushort_t* __restrict__ crossout)
{
    __shared__ __align__(16) char smem[134400];
    ushort_t* Wst = (ushort_t*)smem;             // [64][520] weight stage
    float*    Ss  = (float*)smem;                // [64][216] scores (after weights dead)
    ushort_t* Qs  = (ushort_t*)(smem + 66560);   // [64][72]
    ushort_t* Kc  = (ushort_t*)(smem + 75776);   // [208][72]; Pb [64][224] after
    ushort_t* Pb  = Kc;
    ushort_t* Vt  = (ushort_t*)(smem + 105728);  // [64][224]

    int b = blockIdx.x >> 3, h = blockIdx.x & 7;
    int t = threadIdx.x, wv = t >> 6, lane = t & 63;
    int lr = lane & 15, lq = lane >> 4;
    const ushort_t* atb = attnout + (long)b * 64 * 512;
    const ushort_t* Kbb = Kb + (long)b * 196 * 512;
    const ushort_t* Vbb = Vb + (long)b * 196 * 512;

    // Phase A: qc
    {
        const ushort_t* W = Fqc + h * 64 * 512;
#pragma unroll
        for (int i = 0; i < 16; ++i) {
            int row = i * 4 + wv;
            glds16(W + row * 512 + lane * 8, Wst + row * 520 + lane * 8);
        }
        __syncthreads();
        f32x4 acc[4];
#pragma unroll
        for (int j = 0; j < 4; ++j) acc[j] = (f32x4){0.f, 0.f, 0.f, 0.f};
        const ushort_t* arow = atb + (wv * 16 + lr) * 512;
#pragma unroll 4
        for (int k = 0; k < 16; ++k) {
            short8 a = *(const short8*)(arow + k * 32 + lq * 8);
#pragma unroll
            for (int j = 0; j < 4; ++j) {
                short8 bb = *(const short8*)&Wst[(j * 16 + lr) * 520 + k * 32 + lq * 8];
                acc[j] = mfma16(a, bb, acc[j]);
            }
        }
#pragma unroll
        for (int j = 0; j < 4; ++j)
#pragma unroll
            for (int r = 0; r < 4; ++r) {
                int col = j * 16 + lr;
                Qs[(wv * 16 + lq * 4 + r) * 72 + col] =
                    f2b(acc[j][r] + gql[b * 512 + h * 64 + col]);
            }
    }
    // Phase B: kc then vc (rows padded to 208; garbage rows masked downstream)
#pragma unroll
    for (int mat = 0; mat < 2; ++mat) {
        const ushort_t* W = ((mat == 0) ? Wkc : Wvc) + h * 64 * 512;
        const ushort_t* Src = (mat == 0) ? Kbb : Vbb;
        __syncthreads();
#pragma unroll
        for (int i = 0; i < 16; ++i) {
            int row = i * 4 + wv;
            glds16(W + row * 512 + lane * 8, Wst + row * 520 + lane * 8);
        }
        __syncthreads();
        for (int rt = wv; rt < 13; rt += 4) {
            f32x4 acc[4];
#pragma unroll
            for (int j = 0; j < 4; ++j) acc[j] = (f32x4){0.f, 0.f, 0.f, 0.f};
            const ushort_t* arow = Src + (long)(rt * 16 + lr) * 512;
#pragma unroll 4
            for (int k = 0; k < 16; ++k) {
                short8 a = *(const short8*)(arow + k * 32 + lq * 8);
#pragma unroll
                for (int j = 0; j < 4; ++j) {
                    short8 bb = *(const short8*)&Wst[(j * 16 + lr) * 520 + k * 32 + lq * 8];
                    acc[j] = mfma16(a, bb, acc[j]);
                }
            }
            if (mat == 0) {
#pragma unroll
                for (int j = 0; j < 4; ++j)
#pragma unroll
                    for (int r = 0; r < 4; ++r)
                        Kc[(rt * 16 + lq * 4 + r) * 72 + j * 16 + lr] = f2b(acc[j][r]);
            } else {
#pragma unroll
                for (int j = 0; j < 4; ++j)
#pragma unroll
                    for (int r = 0; r < 4; ++r)
                        Vt[(j * 16 + lr) * 224 + rt * 16 + lq * 4 + r] = f2b(acc[j][r]);
            }
        }
    }
    __syncthreads();
    // zero Vt pad cols 196..223 (kill garbage incl. NaN before PV MFMA)
    for (int e = t; e < 64 * 28; e += 256) Vt[(e / 28) * 224 + 196 + (e % 28)] = 0;

    // Phase C: S = Qc @ Kc^T  (64 x 208)
    f32x4 sc[13];
#pragma unroll
    for (int ct = 0; ct < 13; ++ct) sc[ct] = (f32x4){0.f, 0.f, 0.f, 0.f};
#pragma unroll
    for (int k2 = 0; k2 < 2; ++k2) {
        short8 a = *(const short8*)&Qs[(wv * 16 + lr) * 72 + k2 * 32 + lq * 8];
#pragma unroll
        for (int ct = 0; ct < 13; ++ct) {
            short8 bb = *(const short8*)&Kc[(ct * 16 + lr) * 72 + k2 * 32 + lq * 8];
            sc[ct] = mfma16(a, bb, sc[ct]);
        }
    }
#pragma unroll
    for (int ct = 0; ct < 13; ++ct)
#pragma unroll
        for (int r = 0; r < 4; ++r)
            Ss[(wv * 16 + lq * 4 + r) * 216 + ct * 16 + lr] = sc[ct][r];
    __syncthreads();

    // Phase D: softmax over 196 cols; P bf16 into Kc region (+zero pad cols)
    for (int rr = 0; rr < 16; ++rr) {
        int r = wv * 16 + rr;
        float v0 = Ss[r * 216 + lane] * 0.125f;
        float v1 = Ss[r * 216 + 64 + lane] * 0.125f;
        float v2 = Ss[r * 216 + 128 + lane] * 0.125f;
        float v3 = (lane < 4) ? Ss[r * 216 + 192 + lane] * 0.125f : -INFINITY;
        float m = fmaxf(fmaxf(v0, v1), fmaxf(v2, v3));
        for (int off = 32; off; off >>= 1) m = fmaxf(m, __shfl_xor(m, off));
        float e0 = __expf(v0 - m), e1 = __expf(v1 - m), e2 = __expf(v2 - m);
        float e3 = (lane < 4) ? __expf(v3 - m) : 0.f;
        float su = e0 + e1 + e2 + e3;
        for (int off = 32; off; off >>= 1) su += __shfl_xor(su, off);
        float inv = 1.f / su;
        Pb[r * 224 + lane]       = f2b(e0 * inv);
        Pb[r * 224 + 64 + lane]  = f2b(e1 * inv);
        Pb[r * 224 + 128 + lane] = f2b(e2 * inv);
        if (lane < 4)  Pb[r * 224 + 192 + lane] = f2b(e3 * inv);
        if (lane < 28) Pb[r * 224 + 196 + lane] = 0;
    }
    __syncthreads();

    // Phase E: O = P @ Vc  (K = 224)
    f32x4 ov[4];
#pragma unroll
    for (int j = 0; j < 4; ++j) ov[j] = (f32x4){0.f, 0.f, 0.f, 0.f};
#pragma unroll
    for (int k2 = 0; k2 < 7; ++k2) {
        short8 a = *(const short8*)&Pb[(wv * 16 + lr) * 224 + k2 * 32 + lq * 8];
#pragma unroll
        for (int j = 0; j < 4; ++j) {
            short8 bb = *(const short8*)&Vt[(j * 16 + lr) * 224 + k2 * 32 + lq * 8];
            ov[j] = mfma16(a, bb, ov[j]);
        }
    }
    long obase = ((long)b * 64) * 512 + h * 64;
#pragma unroll
    for (int j = 0; j < 4; ++j)
#pragma unroll
        for (int r = 0; r < 4; ++r)
            crossout[obase + (long)(wv * 16 + lq * 4 + r) * 512 + j * 16 + lr] = f2b(ov[j][r]);
}

// ---------------------------------------------------------------------------
// Softmax over bf16 logits -> fp32 probs. One block per row.
// ---------------------------------------------------------------------------
__global__ __launch_bounds__(256) void softmax_bf(const ushort_t* __restrict__ lg,
                                                  float* __restrict__ out)
{
    __shared__ float red[8];
    long row = blockIdx.x;
    const ushort_t* p = lg + row * 10000L;
    float* po = out + row * 10000L;
    int t = threadIdx.x;
    int w = t >> 6, lane = t & 63;
    float vals[40];
    float mx = -INFINITY;
#pragma unroll
    for (int ii = 0; ii < 40; ++ii) {
        int c = t + (ii << 8);
        if (c < 10000) { float v = b2f(p[c]); vals[ii] = v; mx = fmaxf(mx, v); }
        else vals[ii] = -INFINITY;
    }
    for (int off = 32; off; off >>= 1) mx = fmaxf(mx, __shfl_xor(mx, off));
    if (lane == 0) red[w] = mx;
    __syncthreads();
    mx = fmaxf(fmaxf(red[0], red[1]), fmaxf(red[2], red[3]));
    float s = 0.f;
#pragma unroll
    for (int ii = 0; ii < 40; ++ii) {
        float e = __expf(vals[ii] - mx);
        vals[ii] = e;
        s += e;
    }
    for (int off = 32; off; off >>= 1) s += __shfl_xor(s, off);
    if (lane == 0) red[4 + w] = s;
    __syncthreads();
    s = red[4] + red[5] + red[6] + red[7];
    float inv = 1.0f / s;
#pragma unroll
    for (int ii = 0; ii < 40; ++ii) {
        int c = t + (ii << 8);
        if (c < 10000) po[c] = vals[ii] * inv;
    }
}

// ---------------------------------------------------------------------------
extern "C" void kernel_launch(void* const* d_in, const int* in_sizes, int n_in,
                              void* d_out, int out_size, void* d_ws, size_t ws_size,
                              hipStream_t stream)
{
    const int*   x    = (const int*)d_in[0];
    const float* Kin  = (const float*)d_in[1];
    const float* Vin  = (const float*)d_in[2];
    const float* g    = (const float*)d_in[3];
    const float* emb  = (const float*)d_in[5];
    const float* Wq_s = (const float*)d_in[6];
    const float* Wk_s = (const float*)d_in[7];
    const float* Wv_s = (const float*)d_in[8];
    const float* Wo_s = (const float*)d_in[9];
    const float* Wq_c = (const float*)d_in[10];
    const float* Wg_c = (const float*)d_in[11];
    const float* Wk_c = (const float*)d_in[12];
    const float* Wv_c = (const float*)d_in[13];
    const float* Wo_c = (const float*)d_in[14];
    const float* Wf   = (const float*)d_in[15];
    const float* bf   = (const float*)d_in[16];
    float* out = (float*)d_out;

    float* gq = (float*)d_ws;                                // [6,32,512] fp32
    ushort_t* act0     = (ushort_t*)(gq + 98304);            // [2048,512]
    ushort_t* crossout = act0 + 1048576;
    ushort_t* attnout  = crossout + 1048576;
    ushort_t* K_bf     = attnout + 1048576;                  // [6272,512]
    ushort_t* V_bf     = K_bf + 3211264;
    ushort_t* W8t      = V_bf + 3211264;                     // 48 x [512,512]^T
    ushort_t* Wf_t     = W8t + 48L * S2;                     // [10112,512]
    ushort_t* Wo_sp    = Wf_t + 5177344;                     // 6 x plain
    ushort_t* Wo_cp    = Wo_sp + 6L * S2;                    // 6 x plain
    ushort_t* Fqc_t    = Wo_cp + 6L * S2;                    // 6 x [512,512]
    ushort_t* Fqkv_t   = Fqc_t + 6L * S2;                    // 15 x [512,512]
    ushort_t* Wfin_t   = Fqkv_t + 15L * S2;                  // [10112,512]
    ushort_t* logits   = W8t;                                // reuse after layers

    prep<<<3848, 256, 0, stream>>>(x, emb, Wq_s, Wk_s, Wv_s, Wo_s, Wq_c, Wg_c,
                                   Wk_c, Wv_c, Wo_c, Wf, Kin, Vin, g,
                                   W8t, Wf_t, Wo_sp, Wo_cp, K_bf, V_bf, act0, gq);
    fusew<<<dim3(4, 4, 21), 256, 0, stream>>>(W8t, Wo_sp, Wo_cp, Fqc_t, Fqkv_t);
    // Wfin = (Wo_c[5] @ Wf)^T = Wf_t @ Wo_cp[5]^T  -> [10112,512]
    gemm_bt<<<dim3(4, 79, 1), 256, 0, stream>>>(Wf_t, Wo_cp + 5L * S2, Wfin_t,
                                                512, 512, nullptr);

    for (int l = 0; l < 6; ++l) {
        const ushort_t *A, *Bq, *Bk, *Bv;
        if (l == 0) {
            A = act0;
            Bq = W8t + 0L * 6 * S2; Bk = W8t + 1L * 6 * S2; Bv = W8t + 2L * 6 * S2;
        } else {
            A = crossout;
            Bq = Fqkv_t + (long)((l - 1) * 3) * S2;
            Bk = Bq + S2; Bv = Bq + 2 * S2;
        }
        layer_self<<<256, 256, 0, stream>>>(A, Bq, Bk, Bv, attnout);
        layer_cross<<<256, 256, 0, stream>>>(attnout, K_bf, V_bf,
                                             Fqc_t + (long)l * S2,
                                             W8t + (long)(5 * 6 + l) * S2,
                                             W8t + (long)(6 * 6 + l) * S2,
                                             gq + (long)l * 16384, crossout);
    }

    gemm_bt<<<dim3(79, 16, 1), 256, 0, stream>>>(crossout, Wfin_t, logits,
                                                 10000, 512, bf);
    softmax_bf<<<2048, 256, 0, stream>>>(logits, out);
}

// Round 5
// 655.070 us; speedup vs baseline: 1.1348x; 1.1295x over previous
//
#include <hip/hip_runtime.h>
#include <math.h>

// GlobalAdaptiveDecoder: B=32 S=64 D=512 H=8 DK=DV=64 NR=196 L=6 VOCAB=10000
// Round 8: revert cooperative fusion (XCD-coherence drift + graph-capture
// hazard). kc/vc hoisted out of the layer chain into one batched GEMM
// (kcv_gemm, 12x [6272,512]@[512,512]) with runtime ws_size gate + fallback
// to round-3 cross. softmax_bf vectorized (short8 loads / float4 stores).

#define S2 (512*512)
typedef unsigned short ushort_t;
typedef unsigned int u32;
typedef __attribute__((ext_vector_type(8))) short short8;
typedef __attribute__((ext_vector_type(4))) float f32x4;

__device__ __forceinline__ ushort_t f2b(float f) {
    union { float f; u32 u; } v; v.f = f;
    u32 r = (v.u + 0x7fffu + ((v.u >> 16) & 1u)) >> 16;
    return (ushort_t)r;
}
__device__ __forceinline__ float b2f(ushort_t u) {
    union { u32 u; float f; } v; v.u = ((u32)u) << 16; return v.f;
}
__device__ __forceinline__ void glds16(const void* g, void* l) {
    __builtin_amdgcn_global_load_lds((const __attribute__((address_space(1))) u32*)g,
                                     (__attribute__((address_space(3))) u32*)l,
                                     16, 0, 0);
}
__device__ __forceinline__ f32x4 mfma16(short8 a, short8 b, f32x4 c) {
    return __builtin_amdgcn_mfma_f32_16x16x32_bf16(a, b, c, 0, 0, 0);
}

// ---------------------------------------------------------------------------
// 128x128 MFMA tile body (gemm_bt / fusew / kcv_gemm). C = A @ B^T (+bias),
// bf16 out via LDS-coalesced epilogue. Rows covered by grid; N mult of 8.
// ---------------------------------------------------------------------------
__device__ __forceinline__ void tile128(
    const ushort_t* __restrict__ A, const ushort_t* __restrict__ B,
    ushort_t* __restrict__ Cp, int N, int K, const float* __restrict__ biasc,
    int m0, int n0, ushort_t* As, ushort_t* Bs, ushort_t* Cs)
{
    int t = threadIdx.x;
    int sr = t >> 2, sk = (t & 3) * 8;
    int wv = t >> 6, lane = t & 63;
    int wr = (wv >> 1) * 64, wc = (wv & 1) * 64;
    int lr = lane & 15, lq = lane >> 4;

    f32x4 acc[4][4];
#pragma unroll
    for (int i = 0; i < 4; ++i)
#pragma unroll
        for (int j = 0; j < 4; ++j) acc[i][j] = (f32x4){0.f, 0.f, 0.f, 0.f};

    for (int k0 = 0; k0 < K; k0 += 32) {
        glds16(A + (long)(m0 + sr) * K + k0 + sk,      (void*)(As + t * 8));
        glds16(A + (long)(m0 + sr + 64) * K + k0 + sk, (void*)(As + (t + 256) * 8));
        glds16(B + (long)(n0 + sr) * K + k0 + sk,      (void*)(Bs + t * 8));
        glds16(B + (long)(n0 + sr + 64) * K + k0 + sk, (void*)(Bs + (t + 256) * 8));
        __syncthreads();
        short8 af[4], bfr[4];
#pragma unroll
        for (int i = 0; i < 4; ++i)
            af[i] = *(const short8*)&As[(wr + i * 16 + lr) * 32 + lq * 8];
#pragma unroll
        for (int j = 0; j < 4; ++j)
            bfr[j] = *(const short8*)&Bs[(wc + j * 16 + lr) * 32 + lq * 8];
#pragma unroll
        for (int i = 0; i < 4; ++i)
#pragma unroll
            for (int j = 0; j < 4; ++j)
                acc[i][j] = mfma16(af[i], bfr[j], acc[i][j]);
        __syncthreads();
    }

    ushort_t* Cw = Cs + wv * 16 * 80;
#pragma unroll
    for (int i = 0; i < 4; ++i) {
#pragma unroll
        for (int j = 0; j < 4; ++j) {
            int colg = n0 + wc + j * 16 + lr;
            float bb = (biasc && colg < N) ? biasc[colg] : 0.f;
#pragma unroll
            for (int r = 0; r < 4; ++r)
                Cw[(lq * 4 + r) * 80 + j * 16 + lr] = f2b(acc[i][j][r] + bb);
        }
        __syncthreads();
#pragma unroll
        for (int rr = 0; rr < 2; ++rr) {
            int c = lane + 64 * rr;
            int row = c >> 3, g8 = c & 7;
            uint4 u = *(const uint4*)&Cw[row * 80 + g8 * 8];
            int colg = n0 + wc + g8 * 8;
            int rowg = m0 + wr + i * 16 + row;
            if (colg < N) *(uint4*)&Cp[(long)rowg * N + colg] = u;
        }
        __syncthreads();
    }
}

__global__ __launch_bounds__(256) void gemm_bt(
    const ushort_t* __restrict__ A, const ushort_t* __restrict__ B,
    ushort_t* __restrict__ C, int N, int K, const float* __restrict__ biasc)
{
    __shared__ ushort_t As[128 * 32], Bs[128 * 32];
    __shared__ __align__(16) ushort_t Cs[4 * 16 * 80];
    tile128(A, B, C, N, K, biasc, blockIdx.y * 128, blockIdx.x * 128, As, Bs, Cs);
}

// z<6:  Fqc[l]   = (Wo_s[l] @ Wq_c[l])^T      = Wq_c_t[l]      @ Wo_sp[l]^T
// z>=6: Fqkv[zz] = (Wo_c[l] @ W{m}_s[l+1])^T  = W{m}_s_t[l+1]  @ Wo_cp[l]^T
__global__ __launch_bounds__(256) void fusew(
    const ushort_t* __restrict__ W8t, const ushort_t* __restrict__ Wo_sp,
    const ushort_t* __restrict__ Wo_cp, ushort_t* __restrict__ Fqc_t,
    ushort_t* __restrict__ Fqkv_t)
{
    __shared__ ushort_t As[128 * 32], Bs[128 * 32];
    __shared__ __align__(16) ushort_t Cs[4 * 16 * 80];
    int z = blockIdx.z;
    const ushort_t *A, *B; ushort_t* C;
    if (z < 6)      { A = W8t + (long)(24 + z) * S2; B = Wo_sp + (long)z * S2; C = Fqc_t + (long)z * S2; }
    else { int zz = z - 6, l = zz / 3, m = zz % 3;
           A = W8t + (long)(m * 6 + l + 1) * S2; B = Wo_cp + (long)l * S2; C = Fqkv_t + (long)zz * S2; }
    tile128(A, B, C, 512, 512, nullptr, blockIdx.y * 128, blockIdx.x * 128, As, Bs, Cs);
}

// kc/vc precompute: z = l*2 + isv. kcv[z] = (K_bf or V_bf)[6272,512] @ W^T,
// W = W8t mat (30+l) for K, (36+l) for V. Same k-order/rounding as in-kernel
// path -> bit-identical kc/vc.
__global__ __launch_bounds__(256) void kcv_gemm(
    const ushort_t* __restrict__ Kb, const ushort_t* __restrict__ Vb,
    const ushort_t* __restrict__ W8t, ushort_t* __restrict__ kcv)
{
    __shared__ ushort_t As[128 * 32], Bs[128 * 32];
    __shared__ __align__(16) ushort_t Cs[4 * 16 * 80];
    int z = blockIdx.z, l = z >> 1, isv = z & 1;
    const ushort_t* A = isv ? Vb : Kb;
    const ushort_t* B = W8t + (long)(30 + isv * 6 + l) * S2;
    ushort_t* C = kcv + (long)z * 3211264;
    tile128(A, B, C, 512, 512, nullptr, blockIdx.y * 128, blockIdx.x * 128, As, Bs, Cs);
}

// ---------------------------------------------------------------------------
// prep (ILP-8): weights^T (2 tiles/block, plain Wo fused), Wf^T, K/V bf16,
// embed+PE (fp32 trig), gq. Identical to round-3 version (passing).
// ---------------------------------------------------------------------------
__global__ __launch_bounds__(256) void prep(
    const int* __restrict__ x, const float* __restrict__ emb,
    const float* __restrict__ Wq_s, const float* __restrict__ Wk_s,
    const float* __restrict__ Wv_s, const float* __restrict__ Wo_s,
    const float* __restrict__ Wq_c, const float* __restrict__ Wg_c,
    const float* __restrict__ Wk_c, const float* __restrict__ Wv_c,
    const float* __restrict__ Wo_c, const float* __restrict__ Wf,
    const float* __restrict__ Kin, const float* __restrict__ Vin,
    const float* __restrict__ g,
    ushort_t* __restrict__ W8t, ushort_t* __restrict__ Wf_t,
    ushort_t* __restrict__ Wo_sp, ushort_t* __restrict__ Wo_cp,
    ushort_t* __restrict__ K_bf, ushort_t* __restrict__ V_bf,
    ushort_t* __restrict__ act0, float* __restrict__ gq)
{
    __shared__ float tile[2][64][65];
    int bid = blockIdx.x, t = threadIdx.x;
    if (bid < 1536) {
        int mat = bid >> 5, wsel = mat / 6, l = mat % 6;
        const float* src = (wsel == 0) ? Wq_s : (wsel == 1) ? Wk_s : (wsel == 2) ? Wv_s :
                           (wsel == 3) ? Wo_s : (wsel == 4) ? Wq_c : (wsel == 5) ? Wk_c :
                           (wsel == 6) ? Wv_c : Wo_c;
        src += (long)l * S2;
        ushort_t* dst = W8t + (long)mat * S2;
        ushort_t* plain = (wsel == 3) ? Wo_sp + (long)l * S2
                        : (wsel == 7) ? Wo_cp + (long)l * S2 : nullptr;
        int within = bid & 31;
        int n0 = (within & 7) * 64, kb = (within >> 3) * 128;
        int r0 = t >> 4, c4 = (t & 15) * 4;
        float4 v[2][4];
#pragma unroll
        for (int h2 = 0; h2 < 2; ++h2)
#pragma unroll
            for (int p = 0; p < 4; ++p)
                v[h2][p] = *(const float4*)(src + (long)(kb + h2 * 64 + p * 16 + r0) * 512 + n0 + c4);
#pragma unroll
        for (int h2 = 0; h2 < 2; ++h2)
#pragma unroll
            for (int p = 0; p < 4; ++p) {
                int r = p * 16 + r0;
                tile[h2][c4 + 0][r] = v[h2][p].x; tile[h2][c4 + 1][r] = v[h2][p].y;
                tile[h2][c4 + 2][r] = v[h2][p].z; tile[h2][c4 + 3][r] = v[h2][p].w;
            }
        if (plain) {
#pragma unroll
            for (int h2 = 0; h2 < 2; ++h2)
#pragma unroll
                for (int p = 0; p < 4; ++p) {
                    ushort4 w;
                    w.x = f2b(v[h2][p].x); w.y = f2b(v[h2][p].y);
                    w.z = f2b(v[h2][p].z); w.w = f2b(v[h2][p].w);
                    *(ushort4*)(plain + (long)(kb + h2 * 64 + p * 16 + r0) * 512 + n0 + c4) = w;
                }
        }
        __syncthreads();
#pragma unroll
        for (int h2 = 0; h2 < 2; ++h2)
#pragma unroll
            for (int q = 0; q < 2; ++q) {
                int nl = q * 32 + (t >> 3), k8 = (t & 7) * 8;
                short8 o;
#pragma unroll
                for (int u = 0; u < 8; ++u) o[u] = (short)f2b(tile[h2][nl][k8 + u]);
                *(short8*)(dst + (long)(n0 + nl) * 512 + kb + h2 * 64 + k8) = o;
            }
    } else if (bid < 2168) {
        int id = bid - 1536;
        int n0 = (id % 158) * 64, kb = (id / 158) * 128;
        int r0 = t >> 4, c4 = (t & 15) * 4;
        int n = n0 + c4;
        float4 v[2][4];
#pragma unroll
        for (int h2 = 0; h2 < 2; ++h2)
#pragma unroll
            for (int p = 0; p < 4; ++p) {
                const float* row = Wf + (long)(kb + h2 * 64 + p * 16 + r0) * 10000;
                float4 w;
                if (n + 3 < 10000) {
                    w = *(const float4*)(row + n);
                } else {
                    w.x = (n + 0 < 10000) ? row[n + 0] : 0.f;
                    w.y = (n + 1 < 10000) ? row[n + 1] : 0.f;
                    w.z = (n + 2 < 10000) ? row[n + 2] : 0.f;
                    w.w = (n + 3 < 10000) ? row[n + 3] : 0.f;
                }
                v[h2][p] = w;
            }
#pragma unroll
        for (int h2 = 0; h2 < 2; ++h2)
#pragma unroll
            for (int p = 0; p < 4; ++p) {
                int r = p * 16 + r0;
                tile[h2][c4 + 0][r] = v[h2][p].x; tile[h2][c4 + 1][r] = v[h2][p].y;
                tile[h2][c4 + 2][r] = v[h2][p].z; tile[h2][c4 + 3][r] = v[h2][p].w;
            }
        __syncthreads();
#pragma unroll
        for (int h2 = 0; h2 < 2; ++h2)
#pragma unroll
            for (int q = 0; q < 2; ++q) {
                int nl = q * 32 + (t >> 3), k8 = (t & 7) * 8;
                short8 o;
#pragma unroll
                for (int u = 0; u < 8; ++u) o[u] = (short)f2b(tile[h2][nl][k8 + u]);
                *(short8*)(Wf_t + (long)(n0 + nl) * 512 + kb + h2 * 64 + k8) = o;
            }
    } else if (bid < 2952) {
        int sec = bid - 2168;
        const float* s; ushort_t* o; long fbase;
        if (sec < 392) { s = Kin; o = K_bf; fbase = (long)sec * 2048; }
        else           { s = Vin; o = V_bf; fbase = (long)(sec - 392) * 2048; }
        float4 v[8];
#pragma unroll
        for (int u = 0; u < 8; ++u)
            v[u] = *(const float4*)(s + 4 * (fbase + t + 256 * u));
#pragma unroll
        for (int u = 0; u < 8; ++u) {
            long fi = fbase + t + 256 * u;
            ushort4 w;
            w.x = f2b(v[u].x); w.y = f2b(v[u].y); w.z = f2b(v[u].z); w.w = f2b(v[u].w);
            *(ushort4*)(o + 4 * fi) = w;
        }
    } else if (bid < 3464) {
        long i = (long)(bid - 2952) * 2048 + t * 8;
        long tok = i >> 9;
        int d8 = (int)(i & 511);
        int s = (int)(tok & 63);
        int id = x[tok];
        const float* erow = emb + (long)id * 512 + d8;
        float4 e0 = *(const float4*)(erow);
        float4 e1 = *(const float4*)(erow + 4);
        float ev[8] = {e0.x, e0.y, e0.z, e0.w, e1.x, e1.y, e1.z, e1.w};
        int j0 = d8 >> 1;
        float sf = (float)s;
        short8 o;
#pragma unroll
        for (int u = 0; u < 4; ++u) {
            float invf = expf(-0.035977892f * (float)(j0 + u));
            float ang = sf * invf;
            o[2 * u]     = (short)f2b(ev[2 * u]     + sinf(ang));
            o[2 * u + 1] = (short)f2b(ev[2 * u + 1] + cosf(ang));
        }
        *(short8*)(act0 + i) = o;
    } else {
        __shared__ float gs[512];
        int id = bid - 3464;
        int lb = id >> 1, half = id & 1;
        int l = lb >> 5, b = lb & 31;
        for (int i = t; i < 512; i += 256) gs[i] = g[b * 512 + i];
        __syncthreads();
        int o = half * 256 + t;
        const float* wcol = Wg_c + (long)l * S2 + o;
        float acc = 0.f;
#pragma unroll 8
        for (int i = 0; i < 512; ++i) acc += gs[i] * wcol[(long)i * 512];
        gq[((long)l * 32 + b) * 512 + o] = acc;
    }
}

// ---------------------------------------------------------------------------
// layer_self: per (b,h): q/k/v = act_b @ W slices (MFMA, W staged in LDS),
// causal attention (MFMA scores + fp32 softmax + MFMA PV), attnout bf16.
// Identical to round-3 (passing).
// ---------------------------------------------------------------------------
__global__ __launch_bounds__(256, 1) void layer_self(
    const ushort_t* __restrict__ act,
    const ushort_t* __restrict__ Wq, const ushort_t* __restrict__ Wk,
    const ushort_t* __restrict__ Wv, ushort_t* __restrict__ attnout)
{
    __shared__ __align__(16) char smem[111616];
    ushort_t* Wst = (ushort_t*)smem;             // [64][520]
    ushort_t* Qs  = (ushort_t*)(smem + 66560);   // [64][72]  (P after softmax)
    ushort_t* Ks  = (ushort_t*)(smem + 75776);   // [64][72]
    ushort_t* Vt  = (ushort_t*)(smem + 84992);   // [64][72]  (transposed)
    float*    Ss  = (float*)(smem + 94208);      // [64][68]

    int b = blockIdx.x >> 3, h = blockIdx.x & 7;
    int t = threadIdx.x, wv = t >> 6, lane = t & 63;
    int lr = lane & 15, lq = lane >> 4;
    const ushort_t* actb = act + (long)b * 64 * 512;

    for (int mat = 0; mat < 3; ++mat) {
        const ushort_t* W = ((mat == 0) ? Wq : (mat == 1) ? Wk : Wv) + h * 64 * 512;
        __syncthreads();
#pragma unroll
        for (int i = 0; i < 16; ++i) {
            int row = i * 4 + wv;
            glds16(W + row * 512 + lane * 8, Wst + row * 520 + lane * 8);
        }
        __syncthreads();
        f32x4 acc[4];
#pragma unroll
        for (int j = 0; j < 4; ++j) acc[j] = (f32x4){0.f, 0.f, 0.f, 0.f};
        const ushort_t* arow = actb + (wv * 16 + lr) * 512;
#pragma unroll 4
        for (int k = 0; k < 16; ++k) {
            short8 a = *(const short8*)(arow + k * 32 + lq * 8);
#pragma unroll
            for (int j = 0; j < 4; ++j) {
                short8 bb = *(const short8*)&Wst[(j * 16 + lr) * 520 + k * 32 + lq * 8];
                acc[j] = mfma16(a, bb, acc[j]);
            }
        }
        if (mat == 2) {
#pragma unroll
            for (int j = 0; j < 4; ++j)
#pragma unroll
                for (int r = 0; r < 4; ++r)
                    Vt[(j * 16 + lr) * 72 + wv * 16 + lq * 4 + r] = f2b(acc[j][r]);
        } else {
            ushort_t* Dst = (mat == 0) ? Qs : Ks;
#pragma unroll
            for (int j = 0; j < 4; ++j)
#pragma unroll
                for (int r = 0; r < 4; ++r)
                    Dst[(wv * 16 + lq * 4 + r) * 72 + j * 16 + lr] = f2b(acc[j][r]);
        }
    }
    __syncthreads();

    // scores S = Q @ K^T
    f32x4 sc[4];
#pragma unroll
    for (int j = 0; j < 4; ++j) sc[j] = (f32x4){0.f, 0.f, 0.f, 0.f};
#pragma unroll
    for (int k2 = 0; k2 < 2; ++k2) {
        short8 a = *(const short8*)&Qs[(wv * 16 + lr) * 72 + k2 * 32 + lq * 8];
#pragma unroll
        for (int j = 0; j < 4; ++j) {
            short8 bb = *(const short8*)&Ks[(j * 16 + lr) * 72 + k2 * 32 + lq * 8];
            sc[j] = mfma16(a, bb, sc[j]);
        }
    }
#pragma unroll
    for (int j = 0; j < 4; ++j)
#pragma unroll
        for (int r = 0; r < 4; ++r)
            Ss[(wv * 16 + lq * 4 + r) * 68 + j * 16 + lr] = sc[j][r];
    __syncthreads();

    // causal softmax; P (bf16) overwrites Qs
    for (int rr = 0; rr < 16; ++rr) {
        int r = wv * 16 + rr;
        float sv = (lane <= r) ? Ss[r * 68 + lane] * 0.125f : -INFINITY;
        float m = sv;
        for (int off = 32; off; off >>= 1) m = fmaxf(m, __shfl_xor(m, off));
        float p = __expf(sv - m);
        float su = p;
        for (int off = 32; off; off >>= 1) su += __shfl_xor(su, off);
        Qs[r * 72 + lane] = f2b(p / su);
    }
    __syncthreads();

    // O = P @ V
    f32x4 ov[4];
#pragma unroll
    for (int j = 0; j < 4; ++j) ov[j] = (f32x4){0.f, 0.f, 0.f, 0.f};
#pragma unroll
    for (int k2 = 0; k2 < 2; ++k2) {
        short8 a = *(const short8*)&Qs[(wv * 16 + lr) * 72 + k2 * 32 + lq * 8];
#pragma unroll
        for (int j = 0; j < 4; ++j) {
            short8 bb = *(const short8*)&Vt[(j * 16 + lr) * 72 + k2 * 32 + lq * 8];
            ov[j] = mfma16(a, bb, ov[j]);
        }
    }
    long obase = ((long)b * 64) * 512 + h * 64;
#pragma unroll
    for (int j = 0; j < 4; ++j)
#pragma unroll
        for (int r = 0; r < 4; ++r)
            attnout[obase + (long)(wv * 16 + lq * 4 + r) * 512 + j * 16 + lr] = f2b(ov[j][r]);
}

// ---------------------------------------------------------------------------
// layer_cross (fallback path, round-3 exact): kc/vc computed in-kernel.
// ---------------------------------------------------------------------------
__global__ __launch_bounds__(256, 1) void layer_cross(
    const ushort_t* __restrict__ attnout, const ushort_t* __restrict__ Kb,
    const ushort_t* __restrict__ Vb, const ushort_t* __restrict__ Fqc,
    const ushort_t* __restrict__ Wkc, const ushort_t* __restrict__ Wvc,
    const float* __restrict__ gql, ushort_t* __restrict__ crossout)
{
    __shared__ __align__(16) char smem[134400];
    ushort_t* Wst = (ushort_t*)smem;             // [64][520] weight stage
    float*    Ss  = (float*)smem;                // [64][216] scores (after weights dead)
    ushort_t* Qs  = (ushort_t*)(smem + 66560);   // [64][72]
    ushort_t* Kc  = (ushort_t*)(smem + 75776);   // [208][72]; Pb [64][224] after
    ushort_t* Pb  = Kc;
    ushort_t* Vt  = (ushort_t*)(smem + 105728);  // [64][224]

    int b = blockIdx.x >> 3, h = blockIdx.x & 7;
    int t = threadIdx.x, wv = t >> 6, lane = t & 63;
    int lr = lane & 15, lq = lane >> 4;
    const ushort_t* atb = attnout + (long)b * 64 * 512;
    const ushort_t* Kbb = Kb + (long)b * 196 * 512;
    const ushort_t* Vbb = Vb + (long)b * 196 * 512;

    // Phase A: qc
    {
        const ushort_t* W = Fqc + h * 64 * 512;
#pragma unroll
        for (int i = 0; i < 16; ++i) {
            int row = i * 4 + wv;
            glds16(W + row * 512 + lane * 8, Wst + row * 520 + lane * 8);
        }
        __syncthreads();
        f32x4 acc[4];
#pragma unroll
        for (int j = 0; j < 4; ++j) acc[j] = (f32x4){0.f, 0.f, 0.f, 0.f};
        const ushort_t* arow = atb + (wv * 16 + lr) * 512;
#pragma unroll 4
        for (int k = 0; k < 16; ++k) {
            short8 a = *(const short8*)(arow + k * 32 + lq * 8);
#pragma unroll
            for (int j = 0; j < 4; ++j) {
                short8 bb = *(const short8*)&Wst[(j * 16 + lr) * 520 + k * 32 + lq * 8];
                acc[j] = mfma16(a, bb, acc[j]);
            }
        }
#pragma unroll
        for (int j = 0; j < 4; ++j)
#pragma unroll
            for (int r = 0; r < 4; ++r) {
                int col = j * 16 + lr;
                Qs[(wv * 16 + lq * 4 + r) * 72 + col] =
                    f2b(acc[j][r] + gql[b * 512 + h * 64 + col]);
            }
    }
    // Phase B: kc then vc (rows padded to 208)
#pragma unroll
    for (int mat = 0; mat < 2; ++mat) {
        const ushort_t* W = ((mat == 0) ? Wkc : Wvc) + h * 64 * 512;
        const ushort_t* Src = (mat == 0) ? Kbb : Vbb;
        __syncthreads();
#pragma unroll
        for (int i = 0; i < 16; ++i) {
            int row = i * 4 + wv;
            glds16(W + row * 512 + lane * 8, Wst + row * 520 + lane * 8);
        }
        __syncthreads();
        for (int rt = wv; rt < 13; rt += 4) {
            f32x4 acc[4];
#pragma unroll
            for (int j = 0; j < 4; ++j) acc[j] = (f32x4){0.f, 0.f, 0.f, 0.f};
            const ushort_t* arow = Src + (long)(rt * 16 + lr) * 512;
#pragma unroll 4
            for (int k = 0; k < 16; ++k) {
                short8 a = *(const short8*)(arow + k * 32 + lq * 8);
#pragma unroll
                for (int j = 0; j < 4; ++j) {
                    short8 bb = *(const short8*)&Wst[(j * 16 + lr) * 520 + k * 32 + lq * 8];
                    acc[j] = mfma16(a, bb, acc[j]);
                }
            }
            if (mat == 0) {
#pragma unroll
                for (int j = 0; j < 4; ++j)
#pragma unroll
                    for (int r = 0; r < 4; ++r)
                        Kc[(rt * 16 + lq * 4 + r) * 72 + j * 16 + lr] = f2b(acc[j][r]);
            } else {
#pragma unroll
                for (int j = 0; j < 4; ++j)
#pragma unroll
                    for (int r = 0; r < 4; ++r)
                        Vt[(j * 16 + lr) * 224 + rt * 16 + lq * 4 + r] = f2b(acc[j][r]);
            }
        }
    }
    __syncthreads();
    for (int e = t; e < 64 * 28; e += 256) Vt[(e / 28) * 224 + 196 + (e % 28)] = 0;

    // Phase C: S = Qc @ Kc^T  (64 x 208)
    f32x4 sc[13];
#pragma unroll
    for (int ct = 0; ct < 13; ++ct) sc[ct] = (f32x4){0.f, 0.f, 0.f, 0.f};
#pragma unroll
    for (int k2 = 0; k2 < 2; ++k2) {
        short8 a = *(const short8*)&Qs[(wv * 16 + lr) * 72 + k2 * 32 + lq * 8];
#pragma unroll
        for (int ct = 0; ct < 13; ++ct) {
            short8 bb = *(const short8*)&Kc[(ct * 16 + lr) * 72 + k2 * 32 + lq * 8];
            sc[ct] = mfma16(a, bb, sc[ct]);
        }
    }
#pragma unroll
    for (int ct = 0; ct < 13; ++ct)
#pragma unroll
        for (int r = 0; r < 4; ++r)
            Ss[(wv * 16 + lq * 4 + r) * 216 + ct * 16 + lr] = sc[ct][r];
    __syncthreads();

    // Phase D: softmax over 196 cols; P bf16 into Kc region
    for (int rr = 0; rr < 16; ++rr) {
        int r = wv * 16 + rr;
        float v0 = Ss[r * 216 + lane] * 0.125f;
        float v1 = Ss[r * 216 + 64 + lane] * 0.125f;
        float v2 = Ss[r * 216 + 128 + lane] * 0.125f;
        float v3 = (lane < 4) ? Ss[r * 216 + 192 + lane] * 0.125f : -INFINITY;
        float m = fmaxf(fmaxf(v0, v1), fmaxf(v2, v3));
        for (int off = 32; off; off >>= 1) m = fmaxf(m, __shfl_xor(m, off));
        float e0 = __expf(v0 - m), e1 = __expf(v1 - m), e2 = __expf(v2 - m);
        float e3 = (lane < 4) ? __expf(v3 - m) : 0.f;
        float su = e0 + e1 + e2 + e3;
        for (int off = 32; off; off >>= 1) su += __shfl_xor(su, off);
        float inv = 1.f / su;
        Pb[r * 224 + lane]       = f2b(e0 * inv);
        Pb[r * 224 + 64 + lane]  = f2b(e1 * inv);
        Pb[r * 224 + 128 + lane] = f2b(e2 * inv);
        if (lane < 4)  Pb[r * 224 + 192 + lane] = f2b(e3 * inv);
        if (lane < 28) Pb[r * 224 + 196 + lane] = 0;
    }
    __syncthreads();

    // Phase E: O = P @ Vc  (K = 224)
    f32x4 ov[4];
#pragma unroll
    for (int j = 0; j < 4; ++j) ov[j] = (f32x4){0.f, 0.f, 0.f, 0.f};
#pragma unroll
    for (int k2 = 0; k2 < 7; ++k2) {
        short8 a = *(const short8*)&Pb[(wv * 16 + lr) * 224 + k2 * 32 + lq * 8];
#pragma unroll
        for (int j = 0; j < 4; ++j) {
            short8 bb = *(const short8*)&Vt[(j * 16 + lr) * 224 + k2 * 32 + lq * 8];
            ov[j] = mfma16(a, bb, ov[j]);
        }
    }
    long obase = ((long)b * 64) * 512 + h * 64;
#pragma unroll
    for (int j = 0; j < 4; ++j)
#pragma unroll
        for (int r = 0; r < 4; ++r)
            crossout[obase + (long)(wv * 16 + lq * 4 + r) * 512 + j * 16 + lr] = f2b(ov[j][r]);
}

// ---------------------------------------------------------------------------
// layer_cross_pre: kc/vc read from precomputed kcv (GEMM output) instead of
// being computed in-kernel. Phases A/C/D/E identical to layer_cross.
// ---------------------------------------------------------------------------
__global__ __launch_bounds__(256, 1) void layer_cross_pre(
    const ushort_t* __restrict__ attnout, const ushort_t* __restrict__ kcl,
    const ushort_t* __restrict__ vcl, const ushort_t* __restrict__ Fqc,
    const float* __restrict__ gql, ushort_t* __restrict__ crossout)
{
    __shared__ __align__(16) char smem[134400];
    ushort_t* Wst = (ushort_t*)smem;             // [64][520] weight stage
    float*    Ss  = (float*)smem;                // [64][216] scores (after weights dead)
    ushort_t* Qs  = (ushort_t*)(smem + 66560);   // [64][72]
    ushort_t* Kc  = (ushort_t*)(smem + 75776);   // [208][72]; Pb [64][224] after
    ushort_t* Pb  = Kc;
    ushort_t* Vt  = (ushort_t*)(smem + 105728);  // [64][224]

    int b = blockIdx.x >> 3, h = blockIdx.x & 7;
    int t = threadIdx.x, wv = t >> 6, lane = t & 63;
    int lr = lane & 15, lq = lane >> 4;
    const ushort_t* atb = attnout + (long)b * 64 * 512;

    // Phase A: qc (unchanged)
    {
        const ushort_t* W = Fqc + h * 64 * 512;
#pragma unroll
        for (int i = 0; i < 16; ++i) {
            int row = i * 4 + wv;
            glds16(W + row * 512 + lane * 8, Wst + row * 520 + lane * 8);
        }
        __syncthreads();
        f32x4 acc[4];
#pragma unroll
        for (int j = 0; j < 4; ++j) acc[j] = (f32x4){0.f, 0.f, 0.f, 0.f};
        const ushort_t* arow = atb + (wv * 16 + lr) * 512;
#pragma unroll 4
        for (int k = 0; k < 16; ++k) {
            short8 a = *(const short8*)(arow + k * 32 + lq * 8);
#pragma unroll
            for (int j = 0; j < 4; ++j) {
                short8 bb = *(const short8*)&Wst[(j * 16 + lr) * 520 + k * 32 + lq * 8];
                acc[j] = mfma16(a, bb, acc[j]);
            }
        }
#pragma unroll
        for (int j = 0; j < 4; ++j)
#pragma unroll
            for (int r = 0; r < 4; ++r) {
                int col = j * 16 + lr;
                Qs[(wv * 16 + lq * 4 + r) * 72 + col] =
                    f2b(acc[j][r] + gql[b * 512 + h * 64 + col]);
            }
    }

    // Phase B': stage precomputed kc/vc slices into LDS.
    // Kc[key][d] direct copy (short8; 144-byte row stride is 16B-aligned);
    // Vt[d][key] via in-LDS transpose scatter. Pad rows/cols zeroed.
    {
        const ushort_t* kr = kcl + ((long)b * 196) * 512 + h * 64;
        for (int idx = t; idx < 208 * 8; idx += 256) {
            int key = idx >> 3, d8 = (idx & 7) * 8;
            short8 v = (short8){0, 0, 0, 0, 0, 0, 0, 0};
            if (key < 196) v = *(const short8*)(kr + (long)key * 512 + d8);
            *(short8*)&Kc[key * 72 + d8] = v;
        }
        const ushort_t* vrp = vcl + ((long)b * 196) * 512 + h * 64;
        for (int idx = t; idx < 196 * 8; idx += 256) {
            int key = idx >> 3, d8 = (idx & 7) * 8;
            short8 v = *(const short8*)(vrp + (long)key * 512 + d8);
#pragma unroll
            for (int u = 0; u < 8; ++u) Vt[(d8 + u) * 224 + key] = v[u];
        }
        for (int e = t; e < 64 * 28; e += 256) Vt[(e / 28) * 224 + 196 + (e % 28)] = 0;
    }
    __syncthreads();

    // Phase C: S = Qc @ Kc^T  (64 x 208)
    f32x4 sc[13];
#pragma unroll
    for (int ct = 0; ct < 13; ++ct) sc[ct] = (f32x4){0.f, 0.f, 0.f, 0.f};
#pragma unroll
    for (int k2 = 0; k2 < 2; ++k2) {
        short8 a = *(const short8*)&Qs[(wv * 16 + lr) * 72 + k2 * 32 + lq * 8];
#pragma unroll
        for (int ct = 0; ct < 13; ++ct) {
            short8 bb = *(const short8*)&Kc[(ct * 16 + lr) * 72 + k2 * 32 + lq * 8];
            sc[ct] = mfma16(a, bb, sc[ct]);
        }
    }
#pragma unroll
    for (int ct = 0; ct < 13; ++ct)
#pragma unroll
        for (int r = 0; r < 4; ++r)
            Ss[(wv * 16 + lq * 4 + r) * 216 + ct * 16 + lr] = sc[ct][r];
    __syncthreads();

    // Phase D: softmax over 196 cols; P bf16 into Kc region
    for (int rr = 0; rr < 16; ++rr) {
        int r = wv * 16 + rr;
        float v0 = Ss[r * 216 + lane] * 0.125f;
        float v1 = Ss[r * 216 + 64 + lane] * 0.125f;
        float v2 = Ss[r * 216 + 128 + lane] * 0.125f;
        float v3 = (lane < 4) ? Ss[r * 216 + 192 + lane] * 0.125f : -INFINITY;
        float m = fmaxf(fmaxf(v0, v1), fmaxf(v2, v3));
        for (int off = 32; off; off >>= 1) m = fmaxf(m, __shfl_xor(m, off));
        float e0 = __expf(v0 - m), e1 = __expf(v1 - m), e2 = __expf(v2 - m);
        float e3 = (lane < 4) ? __expf(v3 - m) : 0.f;
        float su = e0 + e1 + e2 + e3;
        for (int off = 32; off; off >>= 1) su += __shfl_xor(su, off);
        float inv = 1.f / su;
        Pb[r * 224 + lane]       = f2b(e0 * inv);
        Pb[r * 224 + 64 + lane]  = f2b(e1 * inv);
        Pb[r * 224 + 128 + lane] = f2b(e2 * inv);
        if (lane < 4)  Pb[r * 224 + 192 + lane] = f2b(e3 * inv);
        if (lane < 28) Pb[r * 224 + 196 + lane] = 0;
    }
    __syncthreads();

    // Phase E: O = P @ Vc  (K = 224)
    f32x4 ov[4];
#pragma unroll
    for (int j = 0; j < 4; ++j) ov[j] = (f32x4){0.f, 0.f, 0.f, 0.f};
#pragma unroll
    for (int k2 = 0; k2 < 7; ++k2) {
        short8 a = *(const short8*)&Pb[(wv * 16 + lr) * 224 + k2 * 32 + lq * 8];
#pragma unroll
        for (int j = 0; j < 4; ++j) {
            short8 bb = *(const short8*)&Vt[(j * 16 + lr) * 224 + k2 * 32 + lq * 8];
            ov[j] = mfma16(a, bb, ov[j]);
        }
    }
    long obase = ((long)b * 64) * 512 + h * 64;
#pragma unroll
    for (int j = 0; j < 4; ++j)
#pragma unroll
        for (int r = 0; r < 4; ++r)
            crossout[obase + (long)(wv * 16 + lq * 4 + r) * 512 + j * 16 + lr] = f2b(ov[j][r]);
}

// ---------------------------------------------------------------------------
// Softmax over bf16 logits -> fp32 probs. One block per row. Vectorized:
// short8 loads (1250 vecs/row exactly), float4 stores.
// ---------------------------------------------------------------------------
__global__ __launch_bounds__(256) void softmax_bf(const ushort_t* __restrict__ lg,
                                                  float* __restrict__ out)
{
    __shared__ float red[8];
    long row = blockIdx.x;
    const ushort_t* p = lg + row * 10000L;
    float* po = out + row * 10000L;
    int t = threadIdx.x;
    int w = t >> 6, lane = t & 63;
    float vals[40];
    float mx = -INFINITY;
#pragma unroll
    for (int i = 0; i < 5; ++i) {
        int vi = t + (i << 8);
        if (vi < 1250) {
            short8 v = *(const short8*)(p + vi * 8);
#pragma unroll
            for (int u = 0; u < 8; ++u) {
                float f = b2f((ushort_t)v[u]);
                vals[i * 8 + u] = f;
                mx = fmaxf(mx, f);
            }
        } else {
#pragma unroll
            for (int u = 0; u < 8; ++u) vals[i * 8 + u] = -INFINITY;
        }
    }
    for (int off = 32; off; off >>= 1) mx = fmaxf(mx, __shfl_xor(mx, off));
    if (lane == 0) red[w] = mx;
    __syncthreads();
    mx = fmaxf(fmaxf(red[0], red[1]), fmaxf(red[2], red[3]));
    float s = 0.f;
#pragma unroll
    for (int ii = 0; ii < 40; ++ii) {
        float e = __expf(vals[ii] - mx);
        vals[ii] = e;
        s += e;
    }
    for (int off = 32; off; off >>= 1) s += __shfl_xor(s, off);
    if (lane == 0) red[4 + w] = s;
    __syncthreads();
    s = red[4] + red[5] + red[6] + red[7];
    float inv = 1.0f / s;
#pragma unroll
    for (int i = 0; i < 5; ++i) {
        int vi = t + (i << 8);
        if (vi < 1250) {
#pragma unroll
            for (int u4 = 0; u4 < 2; ++u4) {
                float4 o;
                o.x = vals[i * 8 + u4 * 4 + 0] * inv;
                o.y = vals[i * 8 + u4 * 4 + 1] * inv;
                o.z = vals[i * 8 + u4 * 4 + 2] * inv;
                o.w = vals[i * 8 + u4 * 4 + 3] * inv;
                *(float4*)(po + vi * 8 + u4 * 4) = o;
            }
        }
    }
}

// ---------------------------------------------------------------------------
extern "C" void kernel_launch(void* const* d_in, const int* in_sizes, int n_in,
                              void* d_out, int out_size, void* d_ws, size_t ws_size,
                              hipStream_t stream)
{
    const int*   x    = (const int*)d_in[0];
    const float* Kin  = (const float*)d_in[1];
    const float* Vin  = (const float*)d_in[2];
    const float* g    = (const float*)d_in[3];
    const float* emb  = (const float*)d_in[5];
    const float* Wq_s = (const float*)d_in[6];
    const float* Wk_s = (const float*)d_in[7];
    const float* Wv_s = (const float*)d_in[8];
    const float* Wo_s = (const float*)d_in[9];
    const float* Wq_c = (const float*)d_in[10];
    const float* Wg_c = (const float*)d_in[11];
    const float* Wk_c = (const float*)d_in[12];
    const float* Wv_c = (const float*)d_in[13];
    const float* Wo_c = (const float*)d_in[14];
    const float* Wf   = (const float*)d_in[15];
    const float* bf   = (const float*)d_in[16];
    float* out = (float*)d_out;

    float* gq = (float*)d_ws;                                // [6,32,512] fp32
    ushort_t* act0     = (ushort_t*)(gq + 98304);            // [2048,512]
    ushort_t* crossout = act0 + 1048576;
    ushort_t* attnout  = crossout + 1048576;
    ushort_t* K_bf     = attnout + 1048576;                  // [6272,512]
    ushort_t* V_bf     = K_bf + 3211264;
    ushort_t* W8t      = V_bf + 3211264;                     // 48 x [512,512]^T
    ushort_t* Wf_t     = W8t + 48L * S2;                     // [10112,512]
    ushort_t* Wo_sp    = Wf_t + 5177344;                     // 6 x plain
    ushort_t* Wo_cp    = Wo_sp + 6L * S2;                    // 6 x plain
    ushort_t* Fqc_t    = Wo_cp + 6L * S2;                    // 6 x [512,512]
    ushort_t* Fqkv_t   = Fqc_t + 6L * S2;                    // 15 x [512,512]
    ushort_t* Wfin_t   = Fqkv_t + 15L * S2;                  // [10112,512]
    ushort_t* kcv      = Wfin_t + 5177344;                   // 12 x [6272,512]
    ushort_t* logits   = W8t;                                // reuse after layers

    // kcv needs (41353216 + 12*3211264)*2 = 159,776,768 bytes of workspace.
    int use_pre = (ws_size >= 159776768ULL) ? 1 : 0;

    prep<<<3848, 256, 0, stream>>>(x, emb, Wq_s, Wk_s, Wv_s, Wo_s, Wq_c, Wg_c,
                                   Wk_c, Wv_c, Wo_c, Wf, Kin, Vin, g,
                                   W8t, Wf_t, Wo_sp, Wo_cp, K_bf, V_bf, act0, gq);
    fusew<<<dim3(4, 4, 21), 256, 0, stream>>>(W8t, Wo_sp, Wo_cp, Fqc_t, Fqkv_t);
    // Wfin = (Wo_c[5] @ Wf)^T = Wf_t @ Wo_cp[5]^T  -> [10112,512]
    gemm_bt<<<dim3(4, 79, 1), 256, 0, stream>>>(Wf_t, Wo_cp + 5L * S2, Wfin_t,
                                                512, 512, nullptr);
    if (use_pre)
        kcv_gemm<<<dim3(4, 49, 12), 256, 0, stream>>>(K_bf, V_bf, W8t, kcv);

    for (int l = 0; l < 6; ++l) {
        const ushort_t *A, *Bq, *Bk, *Bv;
        if (l == 0) {
            A = act0;
            Bq = W8t + 0L * 6 * S2; Bk = W8t + 1L * 6 * S2; Bv = W8t + 2L * 6 * S2;
        } else {
            A = crossout;
            Bq = Fqkv_t + (long)((l - 1) * 3) * S2;
            Bk = Bq + S2; Bv = Bq + 2 * S2;
        }
        layer_self<<<256, 256, 0, stream>>>(A, Bq, Bk, Bv, attnout);
        if (use_pre)
            layer_cross_pre<<<256, 256, 0, stream>>>(attnout,
                                                     kcv + (long)(l * 2) * 3211264,
                                                     kcv + (long)(l * 2 + 1) * 3211264,
                                                     Fqc_t + (long)l * S2,
                                                     gq + (long)l * 16384, crossout);
        else
            layer_cross<<<256, 256, 0, stream>>>(attnout, K_bf, V_bf,
                                                 Fqc_t + (long)l * S2,
                                                 W8t + (long)(5 * 6 + l) * S2,
                                                 W8t + (long)(6 * 6 + l) * S2,
                                                 gq + (long)l * 16384, crossout);
    }

    gemm_bt<<<dim3(79, 16, 1), 256, 0, stream>>>(crossout, Wfin_t, logits,
                                                 10000, 512, bf);
    softmax_bf<<<2048, 256, 0, stream>>>(logits, out);
}